// Round 12
// baseline (239.541 us; speedup 1.0000x reference)
//
#include <hip/hip_runtime.h>
#include <cstddef>

// ---------------------------------------------------------------------------
// _Mutilscal_MHSA — round 12: gemm_pool rebuilt in the m97 geometry.
// 256 threads / 4 waves, each wave owns a 64x64 output quadrant (acc[4][4]):
// per K-step 16 ds_read_b128 feed 32 MFMA (0.5 reads/MFMA vs 0.75 before).
// Single 32 KB LDS buffer + plain 2-barrier schedule (the proven m97 form);
// ~5 blocks/CU. Epilogue (pool + gap LDS reduction, bf16 x) adapted.
// Everything else identical to round 11 (verified).
// ---------------------------------------------------------------------------

static __device__ __forceinline__ float silu_f(float v) {
  return v / (1.f + __expf(-v));
}

typedef __attribute__((ext_vector_type(8))) short short8v;   // bf16x8 frag
typedef __attribute__((ext_vector_type(4))) float f32x4;     // MFMA acc

union FragU { unsigned u[4]; short8v v; uint4 q; };

static __device__ __forceinline__ unsigned short f2bf(float f) {
  unsigned u = __builtin_bit_cast(unsigned, f);
  u += 0x7fffu + ((u >> 16) & 1u);           // round-to-nearest-even
  return (unsigned short)(u >> 16);
}
static __device__ __forceinline__ unsigned packbf(float lo, float hi) {
  return (unsigned)f2bf(lo) | ((unsigned)f2bf(hi) << 16);
}
static __device__ __forceinline__ float bf_lo(unsigned w) {
  return __builtin_bit_cast(float, w << 16);
}
static __device__ __forceinline__ float bf_hi(unsigned w) {
  return __builtin_bit_cast(float, w & 0xffff0000u);
}

// async global->LDS, 16 B per lane (dest wave-linear: base + lane*16)
static __device__ __forceinline__ void gload16(const unsigned* gsrc, unsigned* ldst) {
  __builtin_amdgcn_global_load_lds(
      (const __attribute__((address_space(1))) unsigned*)gsrc,
      (__attribute__((address_space(3))) unsigned*)ldst, 16, 0, 0);
}

// stage one 4096-word img tile via global_load_lds (512 threads, 2x16B each)
static __device__ __forceinline__ void stage_tile_g(const unsigned* __restrict__ src,
                                                    unsigned* dst, int tid) {
  gload16(src + 4 * tid, dst + 4 * tid);
  gload16(src + 4 * (tid + 512), dst + 4 * (tid + 512));
}

// stage one 4096-word img tile with 256 threads (4x16B each, wave-linear)
static __device__ __forceinline__ void stage_tile_g256(const unsigned* __restrict__ src,
                                                       unsigned* dst, int tid) {
#pragma unroll
  for (int k = 0; k < 4; ++k)
    gload16(src + k * 1024 + tid * 4, dst + k * 1024 + tid * 4);
}

// one fragment = one b128 read
static __device__ __forceinline__ short8v load_frag4(const unsigned* P, int ksg, int pos) {
  FragU f;
  f.q = *(const uint4*)(P + (((ksg << 7) + pos) << 2));
  return f.v;
}

// reg-staged fp32 operand: issue loads (early) ...
static __device__ __forceinline__ void xload16(const float* __restrict__ src, int ld,
                                               int tid, float v[16]) {
  const int pos = tid & 127, kg = tid >> 7;
  const float* p = src + pos + (size_t)(kg * 16) * ld;
#pragma unroll
  for (int i = 0; i < 16; ++i) v[i] = p[(size_t)i * ld];
}
// sum of two fp32 arrays (pooled partials)
static __device__ __forceinline__ void xload16_sum2(const float* __restrict__ a,
                                                    const float* __restrict__ b2, int ld,
                                                    int tid, float v[16]) {
  const int pos = tid & 127, kg = tid >> 7;
  const float* pA = a + pos + (size_t)(kg * 16) * ld;
  const float* pB = b2 + pos + (size_t)(kg * 16) * ld;
#pragma unroll
  for (int i = 0; i < 16; ++i) v[i] = pA[(size_t)i * ld] + pB[(size_t)i * ld];
}
// ... pack + LDS write (late)
static __device__ __forceinline__ void xwrite16(const float v[16], unsigned* Xp, int tid) {
  const int pos = tid & 127, kg = tid >> 7;
#pragma unroll
  for (int i2 = 0; i2 < 4; ++i2) {
    const int kq = kg * 4 + i2;
    const int r4 = (kq & 3) + ((kq >> 3) << 2);
    const int sub = (kq >> 2) & 1;
    uint2 wv;
    wv.x = packbf(v[i2 * 4 + 0], v[i2 * 4 + 1]);
    wv.y = packbf(v[i2 * 4 + 2], v[i2 * 4 + 3]);
    *(uint2*)(Xp + (((r4 << 7) + pos) << 2) + sub * 2) = wv;
  }
}
// packed-pair global store of a 64ch x 128pos x slice (coalesced per row)
static __device__ __forceinline__ void xstore_pairs(const float v[16],
                                                    unsigned* __restrict__ Xg_bst,
                                                    int p0, int tid) {
  const int pos = tid & 127, kg = tid >> 7;
#pragma unroll
  for (int m = 0; m < 8; ++m)
    Xg_bst[(size_t)(kg * 8 + m) * 4096 + p0 + pos] = packbf(v[2 * m], v[2 * m + 1]);
}

// legacy single-shot pack-stage (attn Q)
static __device__ __forceinline__ void stage_x_pack(const float* __restrict__ src, int ld,
                                                    unsigned* Xp, int tid) {
  float v[16];
  xload16(src, ld, tid, v);
  xwrite16(v, Xp, tid);
}

#define GEMM_IDS                                            \
  const int tid = threadIdx.x;                              \
  const int w = tid >> 6, lane = tid & 63;                  \
  const int g = lane >> 4, nl = lane & 15;                  \
  const int wr = w >> 1, wc = w & 1;

#define GEMM_KSTEP_B(ACC, XB, WB)                                                  \
  _Pragma("unroll")                                                                \
  for (int ks = 0; ks < 2; ++ks) {                                                 \
    const short8v a0 = load_frag4(WB, ks * 4 + g, wr * 32 + nl);                   \
    const short8v a1 = load_frag4(WB, ks * 4 + g, wr * 32 + 16 + nl);              \
    _Pragma("unroll")                                                              \
    for (int jj = 0; jj < 4; ++jj) {                                               \
      const short8v bfr = load_frag4(XB, ks * 4 + g, wc * 64 + jj * 16 + nl);      \
      ACC[0][jj] = __builtin_amdgcn_mfma_f32_16x16x32_bf16(a0, bfr, ACC[0][jj], 0, 0, 0); \
      ACC[1][jj] = __builtin_amdgcn_mfma_f32_16x16x32_bf16(a1, bfr, ACC[1][jj], 0, 0, 0); \
    }                                                                              \
  }

// ---------------------------------------------------------------------------
// Weight prepack: fp32 W[OC][K] -> img tiles (tile = to*(K/64)+tk).
__global__ __launch_bounds__(256)
void prepack_w_kernel(const float* __restrict__ w01, const float* __restrict__ w03,
                      const float* __restrict__ w13, const float* __restrict__ w23,
                      const float* __restrict__ w3, const float* __restrict__ wkv,
                      unsigned* __restrict__ img)
{
  const int t = blockIdx.x;
  const float* W; int K; int tile; unsigned* base;
  if (t < 8)       { W = w01; K = 512; tile = t;      base = img; }
  else if (t < 16) { W = w03; K = 128; tile = t - 8;  base = img + 32768; }
  else if (t < 24) { W = w13; K = 128; tile = t - 16; base = img + 65536; }
  else if (t < 32) { W = w23; K = 128; tile = t - 24; base = img + 98304; }
  else if (t < 64) { W = w3;  K = 512; tile = t - 32; base = img + 131072; }
  else             { W = wkv; K = 512; tile = t - 64; base = img + 262144; }
  const int nk = K >> 6;
  const int to = tile / nk, tk = tile - to * nk;
  unsigned* dst = base + (size_t)tile * 4096;
  for (int wi = threadIdx.x; wi < 4096; wi += 256) {
    const int r4 = wi >> 9, pos = (wi >> 2) & 127, sub = (wi >> 1) & 1, j = wi & 1;
    const int kq = (r4 & 3) + sub * 4 + ((r4 >> 2) << 3);
    const int k = tk * 64 + 4 * kq + 2 * j;
    const int oc = to * 128 + pos;
    dst[wi] = packbf(W[(size_t)oc * K + k], W[(size_t)oc * K + k + 1]);
  }
}

// ---------------------------------------------------------------------------
// a01 = silu(s01*(w01@x)+b01) as packed bf16 pairs A01p[b][c2][p].
// Also emits Ximg2[b][c2][p] = packed bf16 copy of x (byproduct).
__global__ __launch_bounds__(512)
void gemm_a01_kernel(const float* __restrict__ X, const unsigned* __restrict__ Wimg,
                     const float* __restrict__ sc, const float* __restrict__ bi,
                     unsigned* __restrict__ A01p, unsigned* __restrict__ Ximg2)
{
  const int b = blockIdx.z, p0 = blockIdx.x * 128;
  GEMM_IDS
  __shared__ unsigned Xp[2][4096], Wp[2][4096];
  const float* Xbase = X + (size_t)b * 512 * 4096 + p0;
  unsigned* Xg_b = Ximg2 + (size_t)b * 256 * 4096;

  f32x4 acc[2][4];
#pragma unroll
  for (int i = 0; i < 2; ++i)
#pragma unroll
    for (int jj = 0; jj < 4; ++jj) acc[i][jj] = (f32x4){0.f, 0.f, 0.f, 0.f};

  {
    float vx[16];
    xload16(Xbase, 4096, tid, vx);
    stage_tile_g(Wimg, Wp[0], tid);
    xwrite16(vx, Xp[0], tid);
    xstore_pairs(vx, Xg_b, p0, tid);                 // st=0 slice
  }
  __syncthreads();

  for (int st = 0; st < 8; ++st) {
    const int cur = st & 1;
    float vn[16];
    if (st < 7) {
      xload16(Xbase + (size_t)((st + 1) * 64) * 4096, 4096, tid, vn);
      stage_tile_g(Wimg + (size_t)(st + 1) * 4096, Wp[cur ^ 1], tid);
    }
    GEMM_KSTEP_B(acc, Xp[cur], Wp[cur])
    if (st < 7) {
      xwrite16(vn, Xp[cur ^ 1], tid);
      xstore_pairs(vn, Xg_b + (size_t)(32 * (st + 1)) * 4096, p0, tid);
    }
    __syncthreads();
  }

#pragma unroll
  for (int i = 0; i < 2; ++i) {
    const int base = wr * 32 + i * 16 + 4 * g;
    const float s0_ = sc[base + 0], b0_ = bi[base + 0];
    const float s1_ = sc[base + 1], b1_ = bi[base + 1];
    const float s2_ = sc[base + 2], b2_ = bi[base + 2];
    const float s3_ = sc[base + 3], b3_ = bi[base + 3];
#pragma unroll
    for (int jj = 0; jj < 4; ++jj) {
      const int pos = p0 + wc * 64 + jj * 16 + nl;
      const float v0 = silu_f(s0_ * acc[i][jj][0] + b0_);
      const float v1 = silu_f(s1_ * acc[i][jj][1] + b1_);
      const float v2 = silu_f(s2_ * acc[i][jj][2] + b2_);
      const float v3 = silu_f(s3_ * acc[i][jj][3] + b3_);
      A01p[((size_t)b * 64 + (base >> 1)) * 4096 + pos]     = packbf(v0, v1);
      A01p[((size_t)b * 64 + (base >> 1) + 1) * 4096 + pos] = packbf(v2, v3);
    }
  }
}

// ---------------------------------------------------------------------------
// Depthwise dilated 3x3 + SiLU on packed a01; writes T img tiles directly.
__global__ __launch_bounds__(256)
void dwconv_pack_kernel(const unsigned* __restrict__ A01p, unsigned* __restrict__ Timg,
                        const float* __restrict__ w02, const float* __restrict__ s02, const float* __restrict__ b02,
                        const float* __restrict__ w12, const float* __restrict__ s12, const float* __restrict__ b12,
                        const float* __restrict__ w22, const float* __restrict__ s22, const float* __restrict__ b22)
{
  const int br = blockIdx.z;
  const int yb = blockIdx.y;
  const int b = yb >> 4, t16 = yb & 15, kstep = t16 >> 3, mm = t16 & 7;
  const int kq = (mm & 3) + ((mm >> 2) << 3);
  const int cbase = kstep * 64 + kq * 4;
  const int p = blockIdx.x * 256 + threadIdx.x;
  const int y = p >> 6, xx = p & 63;
  const int d = 3 + 2 * br;

  const float* wsel = br == 0 ? w02 : (br == 1 ? w12 : w22);
  const float* ssel = br == 0 ? s02 : (br == 1 ? s12 : s22);
  const float* bsel = br == 0 ? b02 : (br == 1 ? b12 : b22);

  float sum[8] = {};
  const unsigned* plane0 = A01p + ((size_t)b * 64 + (cbase >> 1)) * 4096;

#pragma unroll
  for (int u = -1; u <= 1; ++u) {
    const int yv = y + u * d;
    if ((unsigned)yv < 64u) {
#pragma unroll
      for (int v = -1; v <= 1; ++v) {
        const int xv = xx + v * d;
        if ((unsigned)xv < 64u) {
          const int idx = yv * 64 + xv;
          const int tap = (u + 1) * 3 + (v + 1);
#pragma unroll
          for (int q = 0; q < 4; ++q) {
            const int sub = q >> 1, jw = q & 1;
            const unsigned wv = plane0[(size_t)(sub * 8 + jw) * 4096 + idx];
            const int ch = cbase + sub * 16 + jw * 2;
            sum[q * 2 + 0] += wsel[(ch + 0) * 9 + tap] * bf_lo(wv);
            sum[q * 2 + 1] += wsel[(ch + 1) * 9 + tap] * bf_hi(wv);
          }
        }
      }
    }
  }

  unsigned wout[4];
#pragma unroll
  for (int h = 0; h < 4; ++h) {
    const int ch = cbase + (h >> 1) * 16 + (h & 1) * 2;
    const float va = silu_f(ssel[ch] * sum[h * 2] + bsel[ch]);
    const float vb = silu_f(ssel[ch + 1] * sum[h * 2 + 1] + bsel[ch + 1]);
    wout[h] = packbf(va, vb);
  }
  const int tile = ((br * 8 + b) * 2 + kstep) * 32 + (p >> 7);
  *(uint4*)(Timg + (size_t)tile * 4096 + (((mm << 7) + (p & 127)) << 2)) = *(uint4*)wout;
}

// ---------------------------------------------------------------------------
// B = sum_i silu(s_i*(W_i @ t_i)+b_i), 2-phase dbuf (round-7 form).
__global__ __launch_bounds__(512)
void gemm3branch_img_kernel(const unsigned* __restrict__ Timg, const unsigned* __restrict__ Wimg3,
                            const float* __restrict__ s0, const float* __restrict__ s1, const float* __restrict__ s2,
                            const float* __restrict__ b0, const float* __restrict__ b1, const float* __restrict__ b2,
                            unsigned* __restrict__ Bimg)
{
  const int b = blockIdx.z, pt = blockIdx.x, oc0 = blockIdx.y * 128;
  GEMM_IDS
  __shared__ unsigned Xp[2][4096], Wp[2][4096];

  float sum[2][4][4] = {};
  f32x4 acc[2][4];
#pragma unroll
  for (int i = 0; i < 2; ++i)
#pragma unroll
    for (int jj = 0; jj < 4; ++jj) acc[i][jj] = (f32x4){0.f, 0.f, 0.f, 0.f};

#define SRC_X3(st) (Timg + (((size_t)(((st) >> 1) * 8 + b) * 2 + ((st) & 1)) * 32 + pt) * 4096)
#define SRC_W3(st) (Wimg3 + (size_t)((st) >> 1) * 32768 + ((size_t)(oc0 >> 7) * 2 + ((st) & 1)) * 4096)

  stage_tile_g(SRC_X3(0), Xp[0], tid);
  stage_tile_g(SRC_W3(0), Wp[0], tid);
  __syncthreads();

  for (int st = 0; st < 6; ++st) {
    const int cur = st & 1;
    if (st < 5) {
      stage_tile_g(SRC_X3(st + 1), Xp[cur ^ 1], tid);
      stage_tile_g(SRC_W3(st + 1), Wp[cur ^ 1], tid);
    }
    GEMM_KSTEP_B(acc, Xp[cur], Wp[cur])
    if (st & 1) {
      const int brn = st >> 1;
      const float* ss = brn == 0 ? s0 : (brn == 1 ? s1 : s2);
      const float* bs = brn == 0 ? b0 : (brn == 1 ? b1 : b2);
#pragma unroll
      for (int i = 0; i < 2; ++i) {
        const int base = oc0 + wr * 32 + i * 16 + 4 * g;
#pragma unroll
        for (int r = 0; r < 4; ++r) {
          const float s = ss[base + r], bb = bs[base + r];
#pragma unroll
          for (int jj = 0; jj < 4; ++jj) {
            sum[i][jj][r] += silu_f(s * acc[i][jj][r] + bb);
            acc[i][jj][r] = 0.f;
          }
        }
      }
    }
    __syncthreads();
  }
#undef SRC_X3
#undef SRC_W3

#pragma unroll
  for (int i = 0; i < 2; ++i) {
    const int ol = wr * 32 + i * 16 + 4 * g;
    const int kstep_g = (oc0 + ol) >> 6;
    const int kin = ol & 63;
    const int kq2 = kin >> 2;
    const int r4 = (kq2 & 3) + ((kq2 >> 3) << 2);
    const int sub = (kq2 >> 2) & 1;
#pragma unroll
    for (int jj = 0; jj < 4; ++jj) {
      const int pos = wc * 64 + jj * 16 + nl;
      uint2 wv;
      wv.x = packbf(sum[i][jj][0], sum[i][jj][1]);
      wv.y = packbf(sum[i][jj][2], sum[i][jj][3]);
      *(uint2*)(Bimg + ((size_t)(b * 8 + kstep_g) * 32 + pt) * 4096 + (((r4 << 7) + pos) << 2) + sub * 2) = wv;
    }
  }
}

// ---------------------------------------------------------------------------
// w3 GEMM (512->512) + fused silu*x + 4x4 pool + gap, m97 geometry:
// 256 thr / 4 waves, each wave 64x64 (acc[4][4]); per K-step 16 b128 reads
// feed 32 MFMA. Single 32 KB LDS buffer, 2-barrier schedule. x from Ximg2.
__global__ __launch_bounds__(256)
void gemm_pool_img_kernel(const unsigned* __restrict__ Bimg, const unsigned* __restrict__ W3img,
                          const float* __restrict__ sc, const float* __restrict__ bi,
                          const unsigned* __restrict__ Ximg2, float* __restrict__ pooled2,
                          float* __restrict__ gapb)
{
  const int b = blockIdx.z, pt = blockIdx.x, oc0 = blockIdx.y * 128;
  const int p0 = pt * 128;
  const unsigned* Xb2 = Ximg2 + (size_t)b * 256 * 4096;
  const int tid = threadIdx.x;
  const int w = tid >> 6, lane = tid & 63;
  const int g = lane >> 4, nl = lane & 15;
  const int wr = w >> 1, wc = w & 1;       // wave -> 64x64 quadrant

  __shared__ unsigned Xp[4096], Wp[4096];  // 32 KB

  f32x4 acc[4][4];
#pragma unroll
  for (int i = 0; i < 4; ++i)
#pragma unroll
    for (int jj = 0; jj < 4; ++jj) acc[i][jj] = (f32x4){0.f, 0.f, 0.f, 0.f};

  for (int st = 0; st < 8; ++st) {
    __syncthreads();                       // protect prior reads of Xp/Wp
    stage_tile_g256(Bimg + ((size_t)(b * 8 + st) * 32 + pt) * 4096, Xp, tid);
    stage_tile_g256(W3img + ((size_t)(oc0 >> 7) * 8 + st) * 4096, Wp, tid);
    __syncthreads();                       // drains vmcnt: tiles ready
#pragma unroll
    for (int ks = 0; ks < 2; ++ks) {
      short8v a[4];
#pragma unroll
      for (int i = 0; i < 4; ++i)
        a[i] = load_frag4(Wp, ks * 4 + g, wr * 64 + i * 16 + nl);
#pragma unroll
      for (int jj = 0; jj < 4; ++jj) {
        const short8v bfr = load_frag4(Xp, ks * 4 + g, wc * 64 + jj * 16 + nl);
#pragma unroll
        for (int i = 0; i < 4; ++i)
          acc[i][jj] = __builtin_amdgcn_mfma_f32_16x16x32_bf16(a[i], bfr, acc[i][jj], 0, 0, 0);
      }
    }
  }
  __syncthreads();                         // all waves done reading Wp

  // ---- LDS reductions: red[128 oc][16 pw] pool cells + gred[128] gap ----
  float* red  = (float*)Wp;                // 2048 floats (16 KB buffer)
  float* gred = red + 2048;                // 128 floats
  for (int e = tid; e < 2176; e += 256) red[e] = 0.f;
  __syncthreads();

  float xsum[4][4] = {};
#pragma unroll
  for (int i = 0; i < 4; ++i) {
    const int olb = wr * 64 + i * 16 + 4 * g;          // oc quad base (mult 4)
    const int oc_ = oc0 + olb;
    const float4 s4 = *(const float4*)(sc + oc_);
    const float4 b4 = *(const float4*)(bi + oc_);
#pragma unroll
    for (int jj = 0; jj < 4; ++jj) {
      const int p = p0 + wc * 64 + jj * 16 + nl;
      const unsigned xw0 = Xb2[(size_t)(oc_ >> 1) * 4096 + p];
      const unsigned xw1 = Xb2[(size_t)((oc_ >> 1) + 1) * 4096 + p];
      const float xv[4] = {bf_lo(xw0), bf_hi(xw0), bf_lo(xw1), bf_hi(xw1)};
      const float sv[4] = {s4.x, s4.y, s4.z, s4.w};
      const float bv[4] = {b4.x, b4.y, b4.z, b4.w};
#pragma unroll
      for (int r = 0; r < 4; ++r) {
        xsum[i][r] += xv[r];
        float val = silu_f(sv[r] * acc[i][jj][r] + bv[r]) * xv[r];
        val += __shfl_xor(val, 1, 64);
        val += __shfl_xor(val, 2, 64);
        if ((nl & 3) == 0) {
          const int col = p & 63;
          atomicAdd(&red[(olb + r) * 16 + (col >> 2)], val);   // LDS atomic
        }
      }
    }
  }
  // gap partials: reduce xsum over the 16 nl lanes, add to gred[ol]
#pragma unroll
  for (int i = 0; i < 4; ++i)
#pragma unroll
    for (int r = 0; r < 4; ++r) {
      float v = xsum[i][r];
      v += __shfl_xor(v, 1, 64);
      v += __shfl_xor(v, 2, 64);
      v += __shfl_xor(v, 4, 64);
      v += __shfl_xor(v, 8, 64);
      if (nl == 0)
        atomicAdd(&gred[wr * 64 + i * 16 + 4 * g + r], v);     // LDS atomic
    }
  __syncthreads();

  {
    const int ph = pt >> 1;
    float* pdst = pooled2 + (size_t)(pt & 1) * (8ull * 512 * 256);
    for (int e = tid; e < 2048; e += 256) {
      const int ol = e >> 4, pw = e & 15;
      pdst[((size_t)b * 512 + oc0 + ol) * 256 + ph * 16 + pw] = red[e] * (1.f / 16.f);
    }
    if (tid < 128)
      atomicAdd(&gapb[b * 512 + oc0 + tid], gred[tid]);        // 128/block global
  }
}

// ---------------------------------------------------------------------------
// kv GEMM (pooledA+pooledB fp32 -> K img + V PV-layout tiles), 2-phase dbuf.
__global__ __launch_bounds__(512)
void gemm_kv_kernel(const float* __restrict__ pooled2, const unsigned* __restrict__ WKVimg,
                    const float* __restrict__ sc, const float* __restrict__ bi,
                    unsigned* __restrict__ Kimg, unsigned* __restrict__ Vimg)
{
  const int b = blockIdx.z, p0 = blockIdx.x * 128, oc0 = blockIdx.y * 128;
  const float* XbA = pooled2 + (size_t)b * 512 * 256 + p0;
  const float* XbB = XbA + 8ull * 512 * 256;
  GEMM_IDS
  __shared__ unsigned Xp[2][4096], Wp[2][4096];

  f32x4 acc[2][4];
#pragma unroll
  for (int i = 0; i < 2; ++i)
#pragma unroll
    for (int jj = 0; jj < 4; ++jj) acc[i][jj] = (f32x4){0.f, 0.f, 0.f, 0.f};

  {
    float vx[16];
    xload16_sum2(XbA, XbB, 256, tid, vx);
    stage_tile_g(WKVimg + (size_t)(oc0 >> 7) * 8 * 4096, Wp[0], tid);
    xwrite16(vx, Xp[0], tid);
  }
  __syncthreads();

  for (int st = 0; st < 8; ++st) {
    const int cur = st & 1;
    float vn[16];
    if (st < 7) {
      xload16_sum2(XbA + (size_t)((st + 1) * 64) * 256, XbB + (size_t)((st + 1) * 64) * 256,
                   256, tid, vn);
      stage_tile_g(WKVimg + ((size_t)(oc0 >> 7) * 8 + st + 1) * 4096, Wp[cur ^ 1], tid);
    }
    GEMM_KSTEP_B(acc, Xp[cur], Wp[cur])
    if (st < 7) xwrite16(vn, Xp[cur ^ 1], tid);
    __syncthreads();
  }

  const bool isK = (oc0 < 512);
#pragma unroll
  for (int i = 0; i < 2; ++i) {
    const int ocb = oc0 + wr * 32 + i * 16 + 4 * g;
#pragma unroll
    for (int jj = 0; jj < 4; ++jj) {
      const int pos = p0 + wc * 64 + jj * 16 + nl;
      float v[4];
#pragma unroll
      for (int r = 0; r < 4; ++r)
        v[r] = silu_f(sc[ocb + r] * acc[i][jj][r] + bi[ocb + r]);
      const int ch = pos >> 7, ml = pos & 127;
      if (isK) {
        const int h = ocb >> 6, d0 = ocb & 63;
        const int kq = d0 >> 2, sub = (kq >> 2) & 1;
        const int r4 = (kq & 3) + ((kq >> 3) << 2);
        unsigned* t = Kimg + ((size_t)(b * 8 + h) * 2 + ch) * 4096;
        uint2 wv;
        wv.x = packbf(v[0] * 0.125f, v[1] * 0.125f);
        wv.y = packbf(v[2] * 0.125f, v[3] * 0.125f);
        *(uint2*)(t + (((r4 << 7) + ml) << 2) + sub * 2) = wv;
      } else {
        const int h = (ocb - 512) >> 6, d0 = (ocb - 512) & 63;
        unsigned* t = Vimg + ((size_t)(b * 8 + h) * 2 + ch) * 4096;
        float ov[4];
#pragma unroll
        for (int r = 0; r < 4; ++r) ov[r] = __shfl_xor(v[r], 1, 64);
        if ((nl & 1) == 0) {
          const int s = (ml >> 1) & 1, m4 = ml >> 2;
#pragma unroll
          for (int r = 0; r < 4; ++r)
            t[((m4 * 64 + d0 + r) << 1) + s] = packbf(v[r], ov[r]);
        }
      }
    }
  }
}

// ---------------------------------------------------------------------------
// SE: gapb holds channel SUMS (fused in pool); scale by 1/4096 here.
__global__ __launch_bounds__(512)
void se_kernel(const float* __restrict__ gap,
               const float* __restrict__ wfc1, const float* __restrict__ bfc1,
               const float* __restrict__ wfc2, const float* __restrict__ bfc2,
               float* __restrict__ gate)
{
  const int b = blockIdx.x, tid = threadIdx.x;
  __shared__ float ylds[128];
  if (tid < 128) {
    float a = 0.f;
    for (int c = 0; c < 512; ++c) a += gap[b * 512 + c] * wfc1[tid * 512 + c];
    a = a * (1.f / 4096.f) + bfc1[tid];
    ylds[tid] = fminf(fmaxf(a, 0.f), 6.f);
  }
  __syncthreads();
  float g = 0.f;
  for (int j = 0; j < 128; ++j) g += ylds[j] * wfc2[tid * 128 + j];
  g += bfc2[tid];
  gate[b * 512 + tid] = 1.f / (1.f + __expf(-g));
}

// ---------------------------------------------------------------------------
// MFMA bf16 attention v3 (unchanged, verified).
__global__ __launch_bounds__(512)
void attn_mfma_kernel(const float* __restrict__ x, const unsigned* __restrict__ Kimg,
                      const unsigned* __restrict__ Vimg,
                      const float* __restrict__ gate, float* __restrict__ out)
{
  const int b = blockIdx.z, h = blockIdx.y;
  const int n0 = blockIdx.x * 128;
  const int tid = threadIdx.x;
  const int w = tid >> 6, lane = tid & 63;
  const int g = lane >> 4, nl = lane & 15;

  __shared__ unsigned lds[20480];          // Qp | K0 | K1 | V0 | V1 (80 KB)
  unsigned* Qp = lds;
  unsigned* Kb0 = lds + 4096;
  unsigned* Kb1 = lds + 8192;
  unsigned* Vb0 = lds + 12288;
  unsigned* Vb1 = lds + 16384;
  float* Osm = (float*)(lds + 4096);       // [64][132] overlay

  const size_t tbase = (size_t)(b * 8 + h) * 2 * 4096;

  stage_tile_g(Kimg + tbase, Kb0, tid);
  stage_tile_g(Vimg + tbase, Vb0, tid);
  stage_x_pack(x + ((size_t)b * 512 + h * 64) * 4096 + n0, 4096, Qp, tid);
  __syncthreads();
  stage_tile_g(Kimg + tbase + 4096, Kb1, tid);
  stage_tile_g(Vimg + tbase + 4096, Vb1, tid);

  float m_run = -1e30f, l_run = 0.f;
  f32x4 o[4];
#pragma unroll
  for (int i = 0; i < 4; ++i) o[i] = (f32x4){0.f, 0.f, 0.f, 0.f};

#pragma unroll
  for (int ch = 0; ch < 2; ++ch) {
    const unsigned* Kp = ch ? Kb1 : Kb0;
    const unsigned* Vp = ch ? Vb1 : Vb0;

    f32x4 s[8];
#pragma unroll
    for (int mb = 0; mb < 8; ++mb) s[mb] = (f32x4){0.f, 0.f, 0.f, 0.f};
#pragma unroll
    for (int ks = 0; ks < 2; ++ks) {
      const short8v qf = load_frag4(Qp, ks * 4 + g, w * 16 + nl);
#pragma unroll
      for (int mb = 0; mb < 8; ++mb) {
        const short8v kf = load_frag4(Kp, ks * 4 + g, mb * 16 + nl);
        s[mb] = __builtin_amdgcn_mfma_f32_16x16x32_bf16(kf, qf, s[mb], 0, 0, 0);
      }
    }

    float cm = -1e30f;
#pragma unroll
    for (int mb = 0; mb < 8; ++mb)
#pragma unroll
      for (int r = 0; r < 4; ++r) cm = fmaxf(cm, s[mb][r]);
    cm = fmaxf(cm, __shfl_xor(cm, 16, 64));
    cm = fmaxf(cm, __shfl_xor(cm, 32, 64));
    const float mnew = fmaxf(m_run, cm);
    const float corr = __expf(m_run - mnew);
    m_run = mnew;
    float cs = 0.f;
#pragma unroll
    for (int mb = 0; mb < 8; ++mb)
#pragma unroll
      for (int r = 0; r < 4; ++r) {
        const float p = __expf(s[mb][r] - mnew);
        s[mb][r] = p;
        cs += p;
      }
    cs += __shfl_xor(cs, 16, 64);
    cs += __shfl_xor(cs, 32, 64);
    l_run = l_run * corr + cs;
#pragma unroll
    for (int db = 0; db < 4; ++db)
#pragma unroll
      for (int r = 0; r < 4; ++r) o[db][r] *= corr;

#pragma unroll
    for (int ks = 0; ks < 4; ++ks) {
      FragU pf;
      pf.u[0] = packbf(s[2 * ks][0],     s[2 * ks][1]);
      pf.u[1] = packbf(s[2 * ks][2],     s[2 * ks][3]);
      pf.u[2] = packbf(s[2 * ks + 1][0], s[2 * ks + 1][1]);
      pf.u[3] = packbf(s[2 * ks + 1][2], s[2 * ks + 1][3]);
#pragma unroll
      for (int db = 0; db < 4; ++db) {
        FragU vf;
        const uint2 lo = *(const uint2*)(Vp + ((8 * ks + g) * 64 + db * 16 + nl) * 2);
        const uint2 hi = *(const uint2*)(Vp + ((8 * ks + 4 + g) * 64 + db * 16 + nl) * 2);
        vf.u[0] = lo.x; vf.u[1] = lo.y; vf.u[2] = hi.x; vf.u[3] = hi.y;
        o[db] = __builtin_amdgcn_mfma_f32_16x16x32_bf16(vf.v, pf.v, o[db], 0, 0, 0);
      }
    }
    __syncthreads();
  }

  const float inv = 1.f / l_run;
#pragma unroll
  for (int db = 0; db < 4; ++db)
#pragma unroll
    for (int r = 0; r < 4; ++r)
      Osm[(db * 16 + 4 * g + r) * 132 + w * 16 + nl] = o[db][r] * inv;
  __syncthreads();

  {
    const int n = tid & 127, t7 = tid >> 7;
    const int jw = t7 >> 1, half = t7 & 1;
#pragma unroll
    for (int i = 0; i < 16; ++i) {
      const int d = t7 + 4 * i;
      const int r4 = (i & 3) + ((i >> 3) << 2);
      const int sub = (i >> 2) & 1;
      const unsigned xw = Qp[(((r4 << 7) + n) << 2) + sub * 2 + jw];
      const float xv = half ? bf_hi(xw) : bf_lo(xw);
      const int c2 = h * 64 + d;
      const size_t off = ((size_t)b * 512 + c2) * 4096 + n0 + n;
      out[off] = Osm[d * 132 + n] + gate[b * 512 + c2] * xv;
    }
  }
}

// ---------------------------------------------------------------------------
extern "C" void kernel_launch(void* const* d_in, const int* in_sizes, int n_in,
                              void* d_out, int out_size, void* d_ws, size_t ws_size,
                              hipStream_t stream)
{
  const float* x    = (const float*)d_in[0];
  const float* w01  = (const float*)d_in[1];
  const float* s01  = (const float*)d_in[2];
  const float* b01  = (const float*)d_in[3];
  const float* w02  = (const float*)d_in[4];
  const float* s02  = (const float*)d_in[5];
  const float* b02  = (const float*)d_in[6];
  const float* w03  = (const float*)d_in[7];
  const float* s03  = (const float*)d_in[8];
  const float* b03  = (const float*)d_in[9];
  const float* w12  = (const float*)d_in[10];
  const float* s12  = (const float*)d_in[11];
  const float* b12  = (const float*)d_in[12];
  const float* w13  = (const float*)d_in[13];
  const float* s13  = (const float*)d_in[14];
  const float* b13  = (const float*)d_in[15];
  const float* w22  = (const float*)d_in[16];
  const float* s22  = (const float*)d_in[17];
  const float* b22  = (const float*)d_in[18];
  const float* w23  = (const float*)d_in[19];
  const float* s23  = (const float*)d_in[20];
  const float* b23  = (const float*)d_in[21];
  const float* w3   = (const float*)d_in[22];
  const float* s3   = (const float*)d_in[23];
  const float* b3   = (const float*)d_in[24];
  const float* wkv  = (const float*)d_in[25];
  const float* skv  = (const float*)d_in[26];
  const float* bkv  = (const float*)d_in[27];
  const float* wfc1 = (const float*)d_in[28];
  const float* bfc1 = (const float*)d_in[29];
  const float* wfc2 = (const float*)d_in[30];
  const float* bfc2 = (const float*)d_in[31];

  float* out = (float*)d_out;
  unsigned* wsu = (unsigned*)d_ws;

  // ws layout (u32 words):
  unsigned* Timg    = wsu;                        // 1536*4096 = 6,291,456
  float*    pooled2 = (float*)(wsu + 6291456);    // 2 x 1,048,576 = 2,097,152
  unsigned* Kimg    = wsu + 8388608;              //   524,288
  unsigned* Vimg    = wsu + 8912896;              //   524,288
  float*    gapb    = (float*)(wsu + 9437184);    //     4,096
  float*    gateb   = (float*)(wsu + 9441280);    //     4,096
  unsigned* Wimg    = wsu + 9445376;              //   524,288 (end 9,969,664 w = 38 MiB)

  // d_out aliasing (lifetimes disjoint):
  unsigned* A01p  = (unsigned*)d_out;             // [0, 2M w), dead after dwconv
  unsigned* Bimg  = (unsigned*)d_out;             // [0, 8M w), dead after pool
  unsigned* Ximg2 = (unsigned*)d_out + 8388608;   // [8M, 16.4M w), dead after pool

  prepack_w_kernel<<<128, 256, 0, stream>>>(w01, w03, w13, w23, w3, wkv, Wimg);
  gemm_a01_kernel<<<dim3(32, 1, 8), 512, 0, stream>>>(x, Wimg, s01, b01, A01p, Ximg2);
  dwconv_pack_kernel<<<dim3(16, 128, 3), 256, 0, stream>>>(A01p, Timg,
      w02, s02, b02, w12, s12, b12, w22, s22, b22);
  gemm3branch_img_kernel<<<dim3(32, 4, 8), 512, 0, stream>>>(Timg, Wimg + 32768,
      s03, s13, s23, b03, b13, b23, Bimg);
  hipMemsetAsync(gapb, 0, 4096 * sizeof(float), stream);
  gemm_pool_img_kernel<<<dim3(32, 4, 8), 256, 0, stream>>>(Bimg, Wimg + 131072,
      s3, b3, Ximg2, pooled2, gapb);
  gemm_kv_kernel<<<dim3(2, 8, 8), 512, 0, stream>>>(pooled2, Wimg + 262144, skv, bkv, Kimg, Vimg);
  se_kernel<<<8, 512, 0, stream>>>(gapb, wfc1, bfc1, wfc2, bfc2, gateb);
  attn_mfma_kernel<<<dim3(32, 8, 8), 512, 0, stream>>>(x, Kimg, Vimg, gateb, out);
}

// Round 13
// 235.905 us; speedup vs baseline: 1.0154x; 1.0154x over previous
//
#include <hip/hip_runtime.h>
#include <cstddef>

// ---------------------------------------------------------------------------
// _Mutilscal_MHSA — round 13: r11 config + XCD-targeted grid swizzle on
// pool/3branch. Staging analysis: pool stages 256 MB/invocation through LDS;
// W3 re-read 256x from L3 because blocks with the same oc-block round-robin
// across all 8 XCDs. Bijective remap: XCD k owns oc-block k>>1 (W slice =
// 0.5 MB -> L2-resident), batches split by parity. Pool kernel itself is the
// proven r11 form (dbuf + counted vmcnt + setprio + bf16 x + fused gap).
// ---------------------------------------------------------------------------

static __device__ __forceinline__ float silu_f(float v) {
  return v / (1.f + __expf(-v));
}

typedef __attribute__((ext_vector_type(8))) short short8v;   // bf16x8 frag
typedef __attribute__((ext_vector_type(4))) float f32x4;     // MFMA acc

union FragU { unsigned u[4]; short8v v; uint4 q; };

#define VM_WAIT(N) asm volatile("s_waitcnt vmcnt(" #N ")" ::: "memory")
#define SBAR()     asm volatile("s_barrier" ::: "memory")

static __device__ __forceinline__ unsigned short f2bf(float f) {
  unsigned u = __builtin_bit_cast(unsigned, f);
  u += 0x7fffu + ((u >> 16) & 1u);           // round-to-nearest-even
  return (unsigned short)(u >> 16);
}
static __device__ __forceinline__ unsigned packbf(float lo, float hi) {
  return (unsigned)f2bf(lo) | ((unsigned)f2bf(hi) << 16);
}
static __device__ __forceinline__ float bf_lo(unsigned w) {
  return __builtin_bit_cast(float, w << 16);
}
static __device__ __forceinline__ float bf_hi(unsigned w) {
  return __builtin_bit_cast(float, w & 0xffff0000u);
}

// async global->LDS, 16 B per lane (dest wave-linear: base + lane*16)
static __device__ __forceinline__ void gload16(const unsigned* gsrc, unsigned* ldst) {
  __builtin_amdgcn_global_load_lds(
      (const __attribute__((address_space(1))) unsigned*)gsrc,
      (__attribute__((address_space(3))) unsigned*)ldst, 16, 0, 0);
}

// stage one 4096-word img tile via global_load_lds (512 threads, 2x16B each)
static __device__ __forceinline__ void stage_tile_g(const unsigned* __restrict__ src,
                                                    unsigned* dst, int tid) {
  gload16(src + 4 * tid, dst + 4 * tid);
  gload16(src + 4 * (tid + 512), dst + 4 * (tid + 512));
}

// one fragment = one b128 read
static __device__ __forceinline__ short8v load_frag4(const unsigned* P, int ksg, int pos) {
  FragU f;
  f.q = *(const uint4*)(P + (((ksg << 7) + pos) << 2));
  return f.v;
}

// reg-staged fp32 operand: issue loads (early) ...
static __device__ __forceinline__ void xload16(const float* __restrict__ src, int ld,
                                               int tid, float v[16]) {
  const int pos = tid & 127, kg = tid >> 7;
  const float* p = src + pos + (size_t)(kg * 16) * ld;
#pragma unroll
  for (int i = 0; i < 16; ++i) v[i] = p[(size_t)i * ld];
}
// sum of two fp32 arrays (pooled partials)
static __device__ __forceinline__ void xload16_sum2(const float* __restrict__ a,
                                                    const float* __restrict__ b2, int ld,
                                                    int tid, float v[16]) {
  const int pos = tid & 127, kg = tid >> 7;
  const float* pA = a + pos + (size_t)(kg * 16) * ld;
  const float* pB = b2 + pos + (size_t)(kg * 16) * ld;
#pragma unroll
  for (int i = 0; i < 16; ++i) v[i] = pA[(size_t)i * ld] + pB[(size_t)i * ld];
}
// ... pack + LDS write (late)
static __device__ __forceinline__ void xwrite16(const float v[16], unsigned* Xp, int tid) {
  const int pos = tid & 127, kg = tid >> 7;
#pragma unroll
  for (int i2 = 0; i2 < 4; ++i2) {
    const int kq = kg * 4 + i2;
    const int r4 = (kq & 3) + ((kq >> 3) << 2);
    const int sub = (kq >> 2) & 1;
    uint2 wv;
    wv.x = packbf(v[i2 * 4 + 0], v[i2 * 4 + 1]);
    wv.y = packbf(v[i2 * 4 + 2], v[i2 * 4 + 3]);
    *(uint2*)(Xp + (((r4 << 7) + pos) << 2) + sub * 2) = wv;
  }
}
// packed-pair global store of a 64ch x 128pos x slice (coalesced per row)
static __device__ __forceinline__ void xstore_pairs(const float v[16],
                                                    unsigned* __restrict__ Xg_bst,
                                                    int p0, int tid) {
  const int pos = tid & 127, kg = tid >> 7;
#pragma unroll
  for (int m = 0; m < 8; ++m)
    Xg_bst[(size_t)(kg * 8 + m) * 4096 + p0 + pos] = packbf(v[2 * m], v[2 * m + 1]);
}

// legacy single-shot pack-stage (attn Q)
static __device__ __forceinline__ void stage_x_pack(const float* __restrict__ src, int ld,
                                                    unsigned* Xp, int tid) {
  float v[16];
  xload16(src, ld, tid, v);
  xwrite16(v, Xp, tid);
}

#define GEMM_IDS                                            \
  const int tid = threadIdx.x;                              \
  const int w = tid >> 6, lane = tid & 63;                  \
  const int g = lane >> 4, nl = lane & 15;                  \
  const int wr = w >> 1, wc = w & 1;

#define GEMM_KSTEP_B(ACC, XB, WB)                                                  \
  _Pragma("unroll")                                                                \
  for (int ks = 0; ks < 2; ++ks) {                                                 \
    const short8v a0 = load_frag4(WB, ks * 4 + g, wr * 32 + nl);                   \
    const short8v a1 = load_frag4(WB, ks * 4 + g, wr * 32 + 16 + nl);              \
    _Pragma("unroll")                                                              \
    for (int jj = 0; jj < 4; ++jj) {                                               \
      const short8v bfr = load_frag4(XB, ks * 4 + g, wc * 64 + jj * 16 + nl);      \
      ACC[0][jj] = __builtin_amdgcn_mfma_f32_16x16x32_bf16(a0, bfr, ACC[0][jj], 0, 0, 0); \
      ACC[1][jj] = __builtin_amdgcn_mfma_f32_16x16x32_bf16(a1, bfr, ACC[1][jj], 0, 0, 0); \
    }                                                                              \
  }

// XCD-targeted decode for 1024-block 1D grids (32 pt x 4 ocb x 8 b).
// XCD = flat&7 (round-robin heuristic). XCD k owns ocb = k>>1; b parity k&1.
#define XCD_DECODE_1024                                     \
  const int flat = blockIdx.x;                              \
  const int k8 = flat & 7, j = flat >> 3;                   \
  const int ocb_ = k8 >> 1;                                 \
  const int b   = (k8 & 1) + ((j >> 5) << 1);               \
  const int pt  = j & 31;                                   \
  const int oc0 = ocb_ * 128;

// ---------------------------------------------------------------------------
// Weight prepack: fp32 W[OC][K] -> img tiles (tile = to*(K/64)+tk).
__global__ __launch_bounds__(256)
void prepack_w_kernel(const float* __restrict__ w01, const float* __restrict__ w03,
                      const float* __restrict__ w13, const float* __restrict__ w23,
                      const float* __restrict__ w3, const float* __restrict__ wkv,
                      unsigned* __restrict__ img)
{
  const int t = blockIdx.x;
  const float* W; int K; int tile; unsigned* base;
  if (t < 8)       { W = w01; K = 512; tile = t;      base = img; }
  else if (t < 16) { W = w03; K = 128; tile = t - 8;  base = img + 32768; }
  else if (t < 24) { W = w13; K = 128; tile = t - 16; base = img + 65536; }
  else if (t < 32) { W = w23; K = 128; tile = t - 24; base = img + 98304; }
  else if (t < 64) { W = w3;  K = 512; tile = t - 32; base = img + 131072; }
  else             { W = wkv; K = 512; tile = t - 64; base = img + 262144; }
  const int nk = K >> 6;
  const int to = tile / nk, tk = tile - to * nk;
  unsigned* dst = base + (size_t)tile * 4096;
  for (int wi = threadIdx.x; wi < 4096; wi += 256) {
    const int r4 = wi >> 9, pos = (wi >> 2) & 127, sub = (wi >> 1) & 1, j = wi & 1;
    const int kq = (r4 & 3) + sub * 4 + ((r4 >> 2) << 3);
    const int k = tk * 64 + 4 * kq + 2 * j;
    const int oc = to * 128 + pos;
    dst[wi] = packbf(W[(size_t)oc * K + k], W[(size_t)oc * K + k + 1]);
  }
}

// ---------------------------------------------------------------------------
// a01 = silu(s01*(w01@x)+b01) as packed bf16 pairs A01p[b][c2][p].
// Also emits Ximg2[b][c2][p] = packed bf16 copy of x (byproduct).
__global__ __launch_bounds__(512)
void gemm_a01_kernel(const float* __restrict__ X, const unsigned* __restrict__ Wimg,
                     const float* __restrict__ sc, const float* __restrict__ bi,
                     unsigned* __restrict__ A01p, unsigned* __restrict__ Ximg2)
{
  const int b = blockIdx.z, p0 = blockIdx.x * 128;
  GEMM_IDS
  __shared__ unsigned Xp[2][4096], Wp[2][4096];
  const float* Xbase = X + (size_t)b * 512 * 4096 + p0;
  unsigned* Xg_b = Ximg2 + (size_t)b * 256 * 4096;

  f32x4 acc[2][4];
#pragma unroll
  for (int i = 0; i < 2; ++i)
#pragma unroll
    for (int jj = 0; jj < 4; ++jj) acc[i][jj] = (f32x4){0.f, 0.f, 0.f, 0.f};

  {
    float vx[16];
    xload16(Xbase, 4096, tid, vx);
    stage_tile_g(Wimg, Wp[0], tid);
    xwrite16(vx, Xp[0], tid);
    xstore_pairs(vx, Xg_b, p0, tid);                 // st=0 slice
  }
  __syncthreads();

  for (int st = 0; st < 8; ++st) {
    const int cur = st & 1;
    float vn[16];
    if (st < 7) {
      xload16(Xbase + (size_t)((st + 1) * 64) * 4096, 4096, tid, vn);
      stage_tile_g(Wimg + (size_t)(st + 1) * 4096, Wp[cur ^ 1], tid);
    }
    GEMM_KSTEP_B(acc, Xp[cur], Wp[cur])
    if (st < 7) {
      xwrite16(vn, Xp[cur ^ 1], tid);
      xstore_pairs(vn, Xg_b + (size_t)(32 * (st + 1)) * 4096, p0, tid);
    }
    __syncthreads();
  }

#pragma unroll
  for (int i = 0; i < 2; ++i) {
    const int base = wr * 32 + i * 16 + 4 * g;
    const float s0_ = sc[base + 0], b0_ = bi[base + 0];
    const float s1_ = sc[base + 1], b1_ = bi[base + 1];
    const float s2_ = sc[base + 2], b2_ = bi[base + 2];
    const float s3_ = sc[base + 3], b3_ = bi[base + 3];
#pragma unroll
    for (int jj = 0; jj < 4; ++jj) {
      const int pos = p0 + wc * 64 + jj * 16 + nl;
      const float v0 = silu_f(s0_ * acc[i][jj][0] + b0_);
      const float v1 = silu_f(s1_ * acc[i][jj][1] + b1_);
      const float v2 = silu_f(s2_ * acc[i][jj][2] + b2_);
      const float v3 = silu_f(s3_ * acc[i][jj][3] + b3_);
      A01p[((size_t)b * 64 + (base >> 1)) * 4096 + pos]     = packbf(v0, v1);
      A01p[((size_t)b * 64 + (base >> 1) + 1) * 4096 + pos] = packbf(v2, v3);
    }
  }
}

// ---------------------------------------------------------------------------
// Depthwise dilated 3x3 + SiLU on packed a01; writes T img tiles directly.
__global__ __launch_bounds__(256)
void dwconv_pack_kernel(const unsigned* __restrict__ A01p, unsigned* __restrict__ Timg,
                        const float* __restrict__ w02, const float* __restrict__ s02, const float* __restrict__ b02,
                        const float* __restrict__ w12, const float* __restrict__ s12, const float* __restrict__ b12,
                        const float* __restrict__ w22, const float* __restrict__ s22, const float* __restrict__ b22)
{
  const int br = blockIdx.z;
  const int yb = blockIdx.y;
  const int b = yb >> 4, t16 = yb & 15, kstep = t16 >> 3, mm = t16 & 7;
  const int kq = (mm & 3) + ((mm >> 2) << 3);
  const int cbase = kstep * 64 + kq * 4;
  const int p = blockIdx.x * 256 + threadIdx.x;
  const int y = p >> 6, xx = p & 63;
  const int d = 3 + 2 * br;

  const float* wsel = br == 0 ? w02 : (br == 1 ? w12 : w22);
  const float* ssel = br == 0 ? s02 : (br == 1 ? s12 : s22);
  const float* bsel = br == 0 ? b02 : (br == 1 ? b12 : b22);

  float sum[8] = {};
  const unsigned* plane0 = A01p + ((size_t)b * 64 + (cbase >> 1)) * 4096;

#pragma unroll
  for (int u = -1; u <= 1; ++u) {
    const int yv = y + u * d;
    if ((unsigned)yv < 64u) {
#pragma unroll
      for (int v = -1; v <= 1; ++v) {
        const int xv = xx + v * d;
        if ((unsigned)xv < 64u) {
          const int idx = yv * 64 + xv;
          const int tap = (u + 1) * 3 + (v + 1);
#pragma unroll
          for (int q = 0; q < 4; ++q) {
            const int sub = q >> 1, jw = q & 1;
            const unsigned wv = plane0[(size_t)(sub * 8 + jw) * 4096 + idx];
            const int ch = cbase + sub * 16 + jw * 2;
            sum[q * 2 + 0] += wsel[(ch + 0) * 9 + tap] * bf_lo(wv);
            sum[q * 2 + 1] += wsel[(ch + 1) * 9 + tap] * bf_hi(wv);
          }
        }
      }
    }
  }

  unsigned wout[4];
#pragma unroll
  for (int h = 0; h < 4; ++h) {
    const int ch = cbase + (h >> 1) * 16 + (h & 1) * 2;
    const float va = silu_f(ssel[ch] * sum[h * 2] + bsel[ch]);
    const float vb = silu_f(ssel[ch + 1] * sum[h * 2 + 1] + bsel[ch + 1]);
    wout[h] = packbf(va, vb);
  }
  const int tile = ((br * 8 + b) * 2 + kstep) * 32 + (p >> 7);
  *(uint4*)(Timg + (size_t)tile * 4096 + (((mm << 7) + (p & 127)) << 2)) = *(uint4*)wout;
}

// ---------------------------------------------------------------------------
// B = sum_i silu(s_i*(W_i @ t_i)+b_i), 2-phase dbuf, XCD-swizzled 1D grid.
__global__ __launch_bounds__(512)
void gemm3branch_img_kernel(const unsigned* __restrict__ Timg, const unsigned* __restrict__ Wimg3,
                            const float* __restrict__ s0, const float* __restrict__ s1, const float* __restrict__ s2,
                            const float* __restrict__ b0, const float* __restrict__ b1, const float* __restrict__ b2,
                            unsigned* __restrict__ Bimg)
{
  XCD_DECODE_1024
  GEMM_IDS
  __shared__ unsigned Xp[2][4096], Wp[2][4096];

  float sum[2][4][4] = {};
  f32x4 acc[2][4];
#pragma unroll
  for (int i = 0; i < 2; ++i)
#pragma unroll
    for (int jj = 0; jj < 4; ++jj) acc[i][jj] = (f32x4){0.f, 0.f, 0.f, 0.f};

#define SRC_X3(st) (Timg + (((size_t)(((st) >> 1) * 8 + b) * 2 + ((st) & 1)) * 32 + pt) * 4096)
#define SRC_W3(st) (Wimg3 + (size_t)((st) >> 1) * 32768 + ((size_t)ocb_ * 2 + ((st) & 1)) * 4096)

  stage_tile_g(SRC_X3(0), Xp[0], tid);
  stage_tile_g(SRC_W3(0), Wp[0], tid);
  __syncthreads();

  for (int st = 0; st < 6; ++st) {
    const int cur = st & 1;
    if (st < 5) {
      stage_tile_g(SRC_X3(st + 1), Xp[cur ^ 1], tid);
      stage_tile_g(SRC_W3(st + 1), Wp[cur ^ 1], tid);
    }
    GEMM_KSTEP_B(acc, Xp[cur], Wp[cur])
    if (st & 1) {
      const int brn = st >> 1;
      const float* ss = brn == 0 ? s0 : (brn == 1 ? s1 : s2);
      const float* bs = brn == 0 ? b0 : (brn == 1 ? b1 : b2);
#pragma unroll
      for (int i = 0; i < 2; ++i) {
        const int base = oc0 + wr * 32 + i * 16 + 4 * g;
#pragma unroll
        for (int r = 0; r < 4; ++r) {
          const float s = ss[base + r], bb = bs[base + r];
#pragma unroll
          for (int jj = 0; jj < 4; ++jj) {
            sum[i][jj][r] += silu_f(s * acc[i][jj][r] + bb);
            acc[i][jj][r] = 0.f;
          }
        }
      }
    }
    __syncthreads();
  }
#undef SRC_X3
#undef SRC_W3

#pragma unroll
  for (int i = 0; i < 2; ++i) {
    const int ol = wr * 32 + i * 16 + 4 * g;
    const int kstep_g = (oc0 + ol) >> 6;
    const int kin = ol & 63;
    const int kq2 = kin >> 2;
    const int r4 = (kq2 & 3) + ((kq2 >> 3) << 2);
    const int sub = (kq2 >> 2) & 1;
#pragma unroll
    for (int jj = 0; jj < 4; ++jj) {
      const int pos = wc * 64 + jj * 16 + nl;
      uint2 wv;
      wv.x = packbf(sum[i][jj][0], sum[i][jj][1]);
      wv.y = packbf(sum[i][jj][2], sum[i][jj][3]);
      *(uint2*)(Bimg + ((size_t)(b * 8 + kstep_g) * 32 + pt) * 4096 + (((r4 << 7) + pos) << 2) + sub * 2) = wv;
    }
  }
}

// ---------------------------------------------------------------------------
// w3 GEMM (512->512) + fused silu*x + 4x4 pool + gap. r11 form (dbuf,
// counted vmcnt, setprio, bf16 x from Ximg2) + XCD-swizzled 1D grid.
__global__ __launch_bounds__(512)
void gemm_pool_img_kernel(const unsigned* __restrict__ Bimg, const unsigned* __restrict__ W3img,
                          const float* __restrict__ sc, const float* __restrict__ bi,
                          const unsigned* __restrict__ Ximg2, float* __restrict__ pooled2,
                          float* __restrict__ gapb)
{
  XCD_DECODE_1024
  const int p0 = pt * 128;
  const unsigned* Xb2 = Ximg2 + (size_t)b * 256 * 4096;
  GEMM_IDS
  __shared__ unsigned Xp[2][4096], Wp[2][4096];

  f32x4 acc[2][4];
#pragma unroll
  for (int i = 0; i < 2; ++i)
#pragma unroll
    for (int jj = 0; jj < 4; ++jj) acc[i][jj] = (f32x4){0.f, 0.f, 0.f, 0.f};

#define SRC_XP(st) (Bimg + ((size_t)(b * 8 + (st)) * 32 + pt) * 4096)
#define SRC_WP(st) (W3img + ((size_t)ocb_ * 8 + (st)) * 4096)

  stage_tile_g(SRC_XP(0), Xp[0], tid);
  stage_tile_g(SRC_WP(0), Wp[0], tid);
  stage_tile_g(SRC_XP(1), Xp[1], tid);
  stage_tile_g(SRC_WP(1), Wp[1], tid);

#pragma unroll
  for (int st = 0; st < 8; ++st) {
    const int cur = st & 1;
    if (st < 7) { VM_WAIT(4); } else { VM_WAIT(0); }
    SBAR();
    __builtin_amdgcn_s_setprio(1);
    GEMM_KSTEP_B(acc, Xp[cur], Wp[cur])
    __builtin_amdgcn_s_setprio(0);
    SBAR();
    if (st < 6) {
      stage_tile_g(SRC_XP(st + 2), Xp[cur], tid);
      stage_tile_g(SRC_WP(st + 2), Wp[cur], tid);
    }
  }
#undef SRC_XP
#undef SRC_WP

  // ---- LDS reductions: red[128 oc][16 pw] pool cells + gred[128] gap ----
  float* red  = (float*)Wp[0];           // 2048 floats
  float* gred = red + 2048;              // 128 floats
  for (int e = tid; e < 2176; e += 512) red[e] = 0.f;
  __syncthreads();

  float xsum[2][4] = {};
#pragma unroll
  for (int i = 0; i < 2; ++i) {
    const int olb = wr * 32 + i * 16 + 4 * g;          // oc quad base (mult 4)
    const int oc_ = oc0 + olb;
    const float4 s4 = *(const float4*)(sc + oc_);
    const float4 b4 = *(const float4*)(bi + oc_);
#pragma unroll
    for (int jj = 0; jj < 4; ++jj) {
      const int p = p0 + wc * 64 + jj * 16 + nl;
      const unsigned xw0 = Xb2[(size_t)(oc_ >> 1) * 4096 + p];
      const unsigned xw1 = Xb2[(size_t)((oc_ >> 1) + 1) * 4096 + p];
      const float xv[4] = {bf_lo(xw0), bf_hi(xw0), bf_lo(xw1), bf_hi(xw1)};
      const float sv[4] = {s4.x, s4.y, s4.z, s4.w};
      const float bv[4] = {b4.x, b4.y, b4.z, b4.w};
#pragma unroll
      for (int r = 0; r < 4; ++r) {
        xsum[i][r] += xv[r];
        float val = silu_f(sv[r] * acc[i][jj][r] + bv[r]) * xv[r];
        val += __shfl_xor(val, 1, 64);
        val += __shfl_xor(val, 2, 64);
        if ((nl & 3) == 0) {
          const int col = p & 63;
          atomicAdd(&red[(olb + r) * 16 + (col >> 2)], val);   // LDS atomic
        }
      }
    }
  }
  // gap partials: reduce xsum over the 16 nl lanes, add to gred[ol]
#pragma unroll
  for (int i = 0; i < 2; ++i)
#pragma unroll
    for (int r = 0; r < 4; ++r) {
      float v = xsum[i][r];
      v += __shfl_xor(v, 1, 64);
      v += __shfl_xor(v, 2, 64);
      v += __shfl_xor(v, 4, 64);
      v += __shfl_xor(v, 8, 64);
      if (nl == 0)
        atomicAdd(&gred[wr * 32 + i * 16 + 4 * g + r], v);     // LDS atomic
    }
  __syncthreads();

  {
    const int ph = pt >> 1;
    float* pdst = pooled2 + (size_t)(pt & 1) * (8ull * 512 * 256);
    for (int e = tid; e < 2048; e += 512) {
      const int ol = e >> 4, pw = e & 15;
      pdst[((size_t)b * 512 + oc0 + ol) * 256 + ph * 16 + pw] = red[e] * (1.f / 16.f);
    }
    if (tid < 128)
      atomicAdd(&gapb[b * 512 + oc0 + tid], gred[tid]);        // 128/block global
  }
}

// ---------------------------------------------------------------------------
// kv GEMM (pooledA+pooledB fp32 -> K img + V PV-layout tiles), 2-phase dbuf.
__global__ __launch_bounds__(512)
void gemm_kv_kernel(const float* __restrict__ pooled2, const unsigned* __restrict__ WKVimg,
                    const float* __restrict__ sc, const float* __restrict__ bi,
                    unsigned* __restrict__ Kimg, unsigned* __restrict__ Vimg)
{
  const int b = blockIdx.z, p0 = blockIdx.x * 128, oc0 = blockIdx.y * 128;
  const float* XbA = pooled2 + (size_t)b * 512 * 256 + p0;
  const float* XbB = XbA + 8ull * 512 * 256;
  GEMM_IDS
  __shared__ unsigned Xp[2][4096], Wp[2][4096];

  f32x4 acc[2][4];
#pragma unroll
  for (int i = 0; i < 2; ++i)
#pragma unroll
    for (int jj = 0; jj < 4; ++jj) acc[i][jj] = (f32x4){0.f, 0.f, 0.f, 0.f};

  {
    float vx[16];
    xload16_sum2(XbA, XbB, 256, tid, vx);
    stage_tile_g(WKVimg + (size_t)(oc0 >> 7) * 8 * 4096, Wp[0], tid);
    xwrite16(vx, Xp[0], tid);
  }
  __syncthreads();

  for (int st = 0; st < 8; ++st) {
    const int cur = st & 1;
    float vn[16];
    if (st < 7) {
      xload16_sum2(XbA + (size_t)((st + 1) * 64) * 256, XbB + (size_t)((st + 1) * 64) * 256,
                   256, tid, vn);
      stage_tile_g(WKVimg + ((size_t)(oc0 >> 7) * 8 + st + 1) * 4096, Wp[cur ^ 1], tid);
    }
    GEMM_KSTEP_B(acc, Xp[cur], Wp[cur])
    if (st < 7) xwrite16(vn, Xp[cur ^ 1], tid);
    __syncthreads();
  }

  const bool isK = (oc0 < 512);
#pragma unroll
  for (int i = 0; i < 2; ++i) {
    const int ocb = oc0 + wr * 32 + i * 16 + 4 * g;
#pragma unroll
    for (int jj = 0; jj < 4; ++jj) {
      const int pos = p0 + wc * 64 + jj * 16 + nl;
      float v[4];
#pragma unroll
      for (int r = 0; r < 4; ++r)
        v[r] = silu_f(sc[ocb + r] * acc[i][jj][r] + bi[ocb + r]);
      const int ch = pos >> 7, ml = pos & 127;
      if (isK) {
        const int h = ocb >> 6, d0 = ocb & 63;
        const int kq = d0 >> 2, sub = (kq >> 2) & 1;
        const int r4 = (kq & 3) + ((kq >> 3) << 2);
        unsigned* t = Kimg + ((size_t)(b * 8 + h) * 2 + ch) * 4096;
        uint2 wv;
        wv.x = packbf(v[0] * 0.125f, v[1] * 0.125f);
        wv.y = packbf(v[2] * 0.125f, v[3] * 0.125f);
        *(uint2*)(t + (((r4 << 7) + ml) << 2) + sub * 2) = wv;
      } else {
        const int h = (ocb - 512) >> 6, d0 = (ocb - 512) & 63;
        unsigned* t = Vimg + ((size_t)(b * 8 + h) * 2 + ch) * 4096;
        float ov[4];
#pragma unroll
        for (int r = 0; r < 4; ++r) ov[r] = __shfl_xor(v[r], 1, 64);
        if ((nl & 1) == 0) {
          const int s = (ml >> 1) & 1, m4 = ml >> 2;
#pragma unroll
          for (int r = 0; r < 4; ++r)
            t[((m4 * 64 + d0 + r) << 1) + s] = packbf(v[r], ov[r]);
        }
      }
    }
  }
}

// ---------------------------------------------------------------------------
// SE: gapb holds channel SUMS (fused in pool); scale by 1/4096 here.
__global__ __launch_bounds__(512)
void se_kernel(const float* __restrict__ gap,
               const float* __restrict__ wfc1, const float* __restrict__ bfc1,
               const float* __restrict__ wfc2, const float* __restrict__ bfc2,
               float* __restrict__ gate)
{
  const int b = blockIdx.x, tid = threadIdx.x;
  __shared__ float ylds[128];
  if (tid < 128) {
    float a = 0.f;
    for (int c = 0; c < 512; ++c) a += gap[b * 512 + c] * wfc1[tid * 512 + c];
    a = a * (1.f / 4096.f) + bfc1[tid];
    ylds[tid] = fminf(fmaxf(a, 0.f), 6.f);
  }
  __syncthreads();
  float g = 0.f;
  for (int j = 0; j < 128; ++j) g += ylds[j] * wfc2[tid * 128 + j];
  g += bfc2[tid];
  gate[b * 512 + tid] = 1.f / (1.f + __expf(-g));
}

// ---------------------------------------------------------------------------
// MFMA bf16 attention v3 (unchanged, verified).
__global__ __launch_bounds__(512)
void attn_mfma_kernel(const float* __restrict__ x, const unsigned* __restrict__ Kimg,
                      const unsigned* __restrict__ Vimg,
                      const float* __restrict__ gate, float* __restrict__ out)
{
  const int b = blockIdx.z, h = blockIdx.y;
  const int n0 = blockIdx.x * 128;
  const int tid = threadIdx.x;
  const int w = tid >> 6, lane = tid & 63;
  const int g = lane >> 4, nl = lane & 15;

  __shared__ unsigned lds[20480];          // Qp | K0 | K1 | V0 | V1 (80 KB)
  unsigned* Qp = lds;
  unsigned* Kb0 = lds + 4096;
  unsigned* Kb1 = lds + 8192;
  unsigned* Vb0 = lds + 12288;
  unsigned* Vb1 = lds + 16384;
  float* Osm = (float*)(lds + 4096);       // [64][132] overlay

  const size_t tbase = (size_t)(b * 8 + h) * 2 * 4096;

  stage_tile_g(Kimg + tbase, Kb0, tid);
  stage_tile_g(Vimg + tbase, Vb0, tid);
  stage_x_pack(x + ((size_t)b * 512 + h * 64) * 4096 + n0, 4096, Qp, tid);
  __syncthreads();
  stage_tile_g(Kimg + tbase + 4096, Kb1, tid);
  stage_tile_g(Vimg + tbase + 4096, Vb1, tid);

  float m_run = -1e30f, l_run = 0.f;
  f32x4 o[4];
#pragma unroll
  for (int i = 0; i < 4; ++i) o[i] = (f32x4){0.f, 0.f, 0.f, 0.f};

#pragma unroll
  for (int ch = 0; ch < 2; ++ch) {
    const unsigned* Kp = ch ? Kb1 : Kb0;
    const unsigned* Vp = ch ? Vb1 : Vb0;

    f32x4 s[8];
#pragma unroll
    for (int mb = 0; mb < 8; ++mb) s[mb] = (f32x4){0.f, 0.f, 0.f, 0.f};
#pragma unroll
    for (int ks = 0; ks < 2; ++ks) {
      const short8v qf = load_frag4(Qp, ks * 4 + g, w * 16 + nl);
#pragma unroll
      for (int mb = 0; mb < 8; ++mb) {
        const short8v kf = load_frag4(Kp, ks * 4 + g, mb * 16 + nl);
        s[mb] = __builtin_amdgcn_mfma_f32_16x16x32_bf16(kf, qf, s[mb], 0, 0, 0);
      }
    }

    float cm = -1e30f;
#pragma unroll
    for (int mb = 0; mb < 8; ++mb)
#pragma unroll
      for (int r = 0; r < 4; ++r) cm = fmaxf(cm, s[mb][r]);
    cm = fmaxf(cm, __shfl_xor(cm, 16, 64));
    cm = fmaxf(cm, __shfl_xor(cm, 32, 64));
    const float mnew = fmaxf(m_run, cm);
    const float corr = __expf(m_run - mnew);
    m_run = mnew;
    float cs = 0.f;
#pragma unroll
    for (int mb = 0; mb < 8; ++mb)
#pragma unroll
      for (int r = 0; r < 4; ++r) {
        const float p = __expf(s[mb][r] - mnew);
        s[mb][r] = p;
        cs += p;
      }
    cs += __shfl_xor(cs, 16, 64);
    cs += __shfl_xor(cs, 32, 64);
    l_run = l_run * corr + cs;
#pragma unroll
    for (int db = 0; db < 4; ++db)
#pragma unroll
      for (int r = 0; r < 4; ++r) o[db][r] *= corr;

#pragma unroll
    for (int ks = 0; ks < 4; ++ks) {
      FragU pf;
      pf.u[0] = packbf(s[2 * ks][0],     s[2 * ks][1]);
      pf.u[1] = packbf(s[2 * ks][2],     s[2 * ks][3]);
      pf.u[2] = packbf(s[2 * ks + 1][0], s[2 * ks + 1][1]);
      pf.u[3] = packbf(s[2 * ks + 1][2], s[2 * ks + 1][3]);
#pragma unroll
      for (int db = 0; db < 4; ++db) {
        FragU vf;
        const uint2 lo = *(const uint2*)(Vp + ((8 * ks + g) * 64 + db * 16 + nl) * 2);
        const uint2 hi = *(const uint2*)(Vp + ((8 * ks + 4 + g) * 64 + db * 16 + nl) * 2);
        vf.u[0] = lo.x; vf.u[1] = lo.y; vf.u[2] = hi.x; vf.u[3] = hi.y;
        o[db] = __builtin_amdgcn_mfma_f32_16x16x32_bf16(vf.v, pf.v, o[db], 0, 0, 0);
      }
    }
    __syncthreads();
  }

  const float inv = 1.f / l_run;
#pragma unroll
  for (int db = 0; db < 4; ++db)
#pragma unroll
    for (int r = 0; r < 4; ++r)
      Osm[(db * 16 + 4 * g + r) * 132 + w * 16 + nl] = o[db][r] * inv;
  __syncthreads();

  {
    const int n = tid & 127, t7 = tid >> 7;
    const int jw = t7 >> 1, half = t7 & 1;
#pragma unroll
    for (int i = 0; i < 16; ++i) {
      const int d = t7 + 4 * i;
      const int r4 = (i & 3) + ((i >> 3) << 2);
      const int sub = (i >> 2) & 1;
      const unsigned xw = Qp[(((r4 << 7) + n) << 2) + sub * 2 + jw];
      const float xv = half ? bf_hi(xw) : bf_lo(xw);
      const int c2 = h * 64 + d;
      const size_t off = ((size_t)b * 512 + c2) * 4096 + n0 + n;
      out[off] = Osm[d * 132 + n] + gate[b * 512 + c2] * xv;
    }
  }
}

// ---------------------------------------------------------------------------
extern "C" void kernel_launch(void* const* d_in, const int* in_sizes, int n_in,
                              void* d_out, int out_size, void* d_ws, size_t ws_size,
                              hipStream_t stream)
{
  const float* x    = (const float*)d_in[0];
  const float* w01  = (const float*)d_in[1];
  const float* s01  = (const float*)d_in[2];
  const float* b01  = (const float*)d_in[3];
  const float* w02  = (const float*)d_in[4];
  const float* s02  = (const float*)d_in[5];
  const float* b02  = (const float*)d_in[6];
  const float* w03  = (const float*)d_in[7];
  const float* s03  = (const float*)d_in[8];
  const float* b03  = (const float*)d_in[9];
  const float* w12  = (const float*)d_in[10];
  const float* s12  = (const float*)d_in[11];
  const float* b12  = (const float*)d_in[12];
  const float* w13  = (const float*)d_in[13];
  const float* s13  = (const float*)d_in[14];
  const float* b13  = (const float*)d_in[15];
  const float* w22  = (const float*)d_in[16];
  const float* s22  = (const float*)d_in[17];
  const float* b22  = (const float*)d_in[18];
  const float* w23  = (const float*)d_in[19];
  const float* s23  = (const float*)d_in[20];
  const float* b23  = (const float*)d_in[21];
  const float* w3   = (const float*)d_in[22];
  const float* s3   = (const float*)d_in[23];
  const float* b3   = (const float*)d_in[24];
  const float* wkv  = (const float*)d_in[25];
  const float* skv  = (const float*)d_in[26];
  const float* bkv  = (const float*)d_in[27];
  const float* wfc1 = (const float*)d_in[28];
  const float* bfc1 = (const float*)d_in[29];
  const float* wfc2 = (const float*)d_in[30];
  const float* bfc2 = (const float*)d_in[31];

  float* out = (float*)d_out;
  unsigned* wsu = (unsigned*)d_ws;

  // ws layout (u32 words):
  unsigned* Timg    = wsu;                        // 1536*4096 = 6,291,456
  float*    pooled2 = (float*)(wsu + 6291456);    // 2 x 1,048,576 = 2,097,152
  unsigned* Kimg    = wsu + 8388608;              //   524,288
  unsigned* Vimg    = wsu + 8912896;              //   524,288
  float*    gapb    = (float*)(wsu + 9437184);    //     4,096
  float*    gateb   = (float*)(wsu + 9441280);    //     4,096
  unsigned* Wimg    = wsu + 9445376;              //   524,288 (end 9,969,664 w = 38 MiB)

  // d_out aliasing (lifetimes disjoint):
  unsigned* A01p  = (unsigned*)d_out;             // [0, 2M w), dead after dwconv
  unsigned* Bimg  = (unsigned*)d_out;             // [0, 8M w), dead after pool
  unsigned* Ximg2 = (unsigned*)d_out + 8388608;   // [8M, 16.4M w), dead after pool

  prepack_w_kernel<<<128, 256, 0, stream>>>(w01, w03, w13, w23, w3, wkv, Wimg);
  gemm_a01_kernel<<<dim3(32, 1, 8), 512, 0, stream>>>(x, Wimg, s01, b01, A01p, Ximg2);
  dwconv_pack_kernel<<<dim3(16, 128, 3), 256, 0, stream>>>(A01p, Timg,
      w02, s02, b02, w12, s12, b12, w22, s22, b22);
  gemm3branch_img_kernel<<<1024, 512, 0, stream>>>(Timg, Wimg + 32768,
      s03, s13, s23, b03, b13, b23, Bimg);
  hipMemsetAsync(gapb, 0, 4096 * sizeof(float), stream);
  gemm_pool_img_kernel<<<1024, 512, 0, stream>>>(Bimg, Wimg + 131072,
      s3, b3, Ximg2, pooled2, gapb);
  gemm_kv_kernel<<<dim3(2, 8, 8), 512, 0, stream>>>(pooled2, Wimg + 262144, skv, bkv, Kimg, Vimg);
  se_kernel<<<8, 512, 0, stream>>>(gapb, wfc1, bfc1, wfc2, bfc2, gateb);
  attn_mfma_kernel<<<dim3(32, 8, 8), 512, 0, stream>>>(x, Kimg, Vimg, gateb, out);
}

// Round 14
// 234.824 us; speedup vs baseline: 1.0201x; 1.0046x over previous
//
#include <hip/hip_runtime.h>
#include <cstddef>

// ---------------------------------------------------------------------------
// _Mutilscal_MHSA — round 13: r11 config + XCD-targeted grid swizzle on
// pool/3branch. Staging analysis: pool stages 256 MB/invocation through LDS;
// W3 re-read 256x from L3 because blocks with the same oc-block round-robin
// across all 8 XCDs. Bijective remap: XCD k owns oc-block k>>1 (W slice =
// 0.5 MB -> L2-resident), batches split by parity. Pool kernel itself is the
// proven r11 form (dbuf + counted vmcnt + setprio + bf16 x + fused gap).
// ---------------------------------------------------------------------------

static __device__ __forceinline__ float silu_f(float v) {
  return v / (1.f + __expf(-v));
}

typedef __attribute__((ext_vector_type(8))) short short8v;   // bf16x8 frag
typedef __attribute__((ext_vector_type(4))) float f32x4;     // MFMA acc

union FragU { unsigned u[4]; short8v v; uint4 q; };

#define VM_WAIT(N) asm volatile("s_waitcnt vmcnt(" #N ")" ::: "memory")
#define SBAR()     asm volatile("s_barrier" ::: "memory")

static __device__ __forceinline__ unsigned short f2bf(float f) {
  unsigned u = __builtin_bit_cast(unsigned, f);
  u += 0x7fffu + ((u >> 16) & 1u);           // round-to-nearest-even
  return (unsigned short)(u >> 16);
}
static __device__ __forceinline__ unsigned packbf(float lo, float hi) {
  return (unsigned)f2bf(lo) | ((unsigned)f2bf(hi) << 16);
}
static __device__ __forceinline__ float bf_lo(unsigned w) {
  return __builtin_bit_cast(float, w << 16);
}
static __device__ __forceinline__ float bf_hi(unsigned w) {
  return __builtin_bit_cast(float, w & 0xffff0000u);
}

// async global->LDS, 16 B per lane (dest wave-linear: base + lane*16)
static __device__ __forceinline__ void gload16(const unsigned* gsrc, unsigned* ldst) {
  __builtin_amdgcn_global_load_lds(
      (const __attribute__((address_space(1))) unsigned*)gsrc,
      (__attribute__((address_space(3))) unsigned*)ldst, 16, 0, 0);
}

// stage one 4096-word img tile via global_load_lds (512 threads, 2x16B each)
static __device__ __forceinline__ void stage_tile_g(const unsigned* __restrict__ src,
                                                    unsigned* dst, int tid) {
  gload16(src + 4 * tid, dst + 4 * tid);
  gload16(src + 4 * (tid + 512), dst + 4 * (tid + 512));
}

// one fragment = one b128 read
static __device__ __forceinline__ short8v load_frag4(const unsigned* P, int ksg, int pos) {
  FragU f;
  f.q = *(const uint4*)(P + (((ksg << 7) + pos) << 2));
  return f.v;
}

// reg-staged fp32 operand: issue loads (early) ...
static __device__ __forceinline__ void xload16(const float* __restrict__ src, int ld,
                                               int tid, float v[16]) {
  const int pos = tid & 127, kg = tid >> 7;
  const float* p = src + pos + (size_t)(kg * 16) * ld;
#pragma unroll
  for (int i = 0; i < 16; ++i) v[i] = p[(size_t)i * ld];
}
// sum of two fp32 arrays (pooled partials)
static __device__ __forceinline__ void xload16_sum2(const float* __restrict__ a,
                                                    const float* __restrict__ b2, int ld,
                                                    int tid, float v[16]) {
  const int pos = tid & 127, kg = tid >> 7;
  const float* pA = a + pos + (size_t)(kg * 16) * ld;
  const float* pB = b2 + pos + (size_t)(kg * 16) * ld;
#pragma unroll
  for (int i = 0; i < 16; ++i) v[i] = pA[(size_t)i * ld] + pB[(size_t)i * ld];
}
// ... pack + LDS write (late)
static __device__ __forceinline__ void xwrite16(const float v[16], unsigned* Xp, int tid) {
  const int pos = tid & 127, kg = tid >> 7;
#pragma unroll
  for (int i2 = 0; i2 < 4; ++i2) {
    const int kq = kg * 4 + i2;
    const int r4 = (kq & 3) + ((kq >> 3) << 2);
    const int sub = (kq >> 2) & 1;
    uint2 wv;
    wv.x = packbf(v[i2 * 4 + 0], v[i2 * 4 + 1]);
    wv.y = packbf(v[i2 * 4 + 2], v[i2 * 4 + 3]);
    *(uint2*)(Xp + (((r4 << 7) + pos) << 2) + sub * 2) = wv;
  }
}
// packed-pair global store of a 64ch x 128pos x slice (coalesced per row)
static __device__ __forceinline__ void xstore_pairs(const float v[16],
                                                    unsigned* __restrict__ Xg_bst,
                                                    int p0, int tid) {
  const int pos = tid & 127, kg = tid >> 7;
#pragma unroll
  for (int m = 0; m < 8; ++m)
    Xg_bst[(size_t)(kg * 8 + m) * 4096 + p0 + pos] = packbf(v[2 * m], v[2 * m + 1]);
}

// legacy single-shot pack-stage (attn Q)
static __device__ __forceinline__ void stage_x_pack(const float* __restrict__ src, int ld,
                                                    unsigned* Xp, int tid) {
  float v[16];
  xload16(src, ld, tid, v);
  xwrite16(v, Xp, tid);
}

#define GEMM_IDS                                            \
  const int tid = threadIdx.x;                              \
  const int w = tid >> 6, lane = tid & 63;                  \
  const int g = lane >> 4, nl = lane & 15;                  \
  const int wr = w >> 1, wc = w & 1;

#define GEMM_KSTEP_B(ACC, XB, WB)                                                  \
  _Pragma("unroll")                                                                \
  for (int ks = 0; ks < 2; ++ks) {                                                 \
    const short8v a0 = load_frag4(WB, ks * 4 + g, wr * 32 + nl);                   \
    const short8v a1 = load_frag4(WB, ks * 4 + g, wr * 32 + 16 + nl);              \
    _Pragma("unroll")                                                              \
    for (int jj = 0; jj < 4; ++jj) {                                               \
      const short8v bfr = load_frag4(XB, ks * 4 + g, wc * 64 + jj * 16 + nl);      \
      ACC[0][jj] = __builtin_amdgcn_mfma_f32_16x16x32_bf16(a0, bfr, ACC[0][jj], 0, 0, 0); \
      ACC[1][jj] = __builtin_amdgcn_mfma_f32_16x16x32_bf16(a1, bfr, ACC[1][jj], 0, 0, 0); \
    }                                                                              \
  }

// XCD-targeted decode for 1024-block 1D grids (32 pt x 4 ocb x 8 b).
// XCD = flat&7 (round-robin heuristic). XCD k owns ocb = k>>1; b parity k&1.
#define XCD_DECODE_1024                                     \
  const int flat = blockIdx.x;                              \
  const int k8 = flat & 7, j = flat >> 3;                   \
  const int ocb_ = k8 >> 1;                                 \
  const int b   = (k8 & 1) + ((j >> 5) << 1);               \
  const int pt  = j & 31;                                   \
  const int oc0 = ocb_ * 128;

// ---------------------------------------------------------------------------
// Weight prepack: fp32 W[OC][K] -> img tiles (tile = to*(K/64)+tk).
__global__ __launch_bounds__(256)
void prepack_w_kernel(const float* __restrict__ w01, const float* __restrict__ w03,
                      const float* __restrict__ w13, const float* __restrict__ w23,
                      const float* __restrict__ w3, const float* __restrict__ wkv,
                      unsigned* __restrict__ img)
{
  const int t = blockIdx.x;
  const float* W; int K; int tile; unsigned* base;
  if (t < 8)       { W = w01; K = 512; tile = t;      base = img; }
  else if (t < 16) { W = w03; K = 128; tile = t - 8;  base = img + 32768; }
  else if (t < 24) { W = w13; K = 128; tile = t - 16; base = img + 65536; }
  else if (t < 32) { W = w23; K = 128; tile = t - 24; base = img + 98304; }
  else if (t < 64) { W = w3;  K = 512; tile = t - 32; base = img + 131072; }
  else             { W = wkv; K = 512; tile = t - 64; base = img + 262144; }
  const int nk = K >> 6;
  const int to = tile / nk, tk = tile - to * nk;
  unsigned* dst = base + (size_t)tile * 4096;
  for (int wi = threadIdx.x; wi < 4096; wi += 256) {
    const int r4 = wi >> 9, pos = (wi >> 2) & 127, sub = (wi >> 1) & 1, j = wi & 1;
    const int kq = (r4 & 3) + sub * 4 + ((r4 >> 2) << 3);
    const int k = tk * 64 + 4 * kq + 2 * j;
    const int oc = to * 128 + pos;
    dst[wi] = packbf(W[(size_t)oc * K + k], W[(size_t)oc * K + k + 1]);
  }
}

// ---------------------------------------------------------------------------
// a01 = silu(s01*(w01@x)+b01) as packed bf16 pairs A01p[b][c2][p].
// Also emits Ximg2[b][c2][p] = packed bf16 copy of x (byproduct).
__global__ __launch_bounds__(512)
void gemm_a01_kernel(const float* __restrict__ X, const unsigned* __restrict__ Wimg,
                     const float* __restrict__ sc, const float* __restrict__ bi,
                     unsigned* __restrict__ A01p, unsigned* __restrict__ Ximg2)
{
  const int b = blockIdx.z, p0 = blockIdx.x * 128;
  GEMM_IDS
  __shared__ unsigned Xp[2][4096], Wp[2][4096];
  const float* Xbase = X + (size_t)b * 512 * 4096 + p0;
  unsigned* Xg_b = Ximg2 + (size_t)b * 256 * 4096;

  f32x4 acc[2][4];
#pragma unroll
  for (int i = 0; i < 2; ++i)
#pragma unroll
    for (int jj = 0; jj < 4; ++jj) acc[i][jj] = (f32x4){0.f, 0.f, 0.f, 0.f};

  {
    float vx[16];
    xload16(Xbase, 4096, tid, vx);
    stage_tile_g(Wimg, Wp[0], tid);
    xwrite16(vx, Xp[0], tid);
    xstore_pairs(vx, Xg_b, p0, tid);                 // st=0 slice
  }
  __syncthreads();

  for (int st = 0; st < 8; ++st) {
    const int cur = st & 1;
    float vn[16];
    if (st < 7) {
      xload16(Xbase + (size_t)((st + 1) * 64) * 4096, 4096, tid, vn);
      stage_tile_g(Wimg + (size_t)(st + 1) * 4096, Wp[cur ^ 1], tid);
    }
    GEMM_KSTEP_B(acc, Xp[cur], Wp[cur])
    if (st < 7) {
      xwrite16(vn, Xp[cur ^ 1], tid);
      xstore_pairs(vn, Xg_b + (size_t)(32 * (st + 1)) * 4096, p0, tid);
    }
    __syncthreads();
  }

#pragma unroll
  for (int i = 0; i < 2; ++i) {
    const int base = wr * 32 + i * 16 + 4 * g;
    const float s0_ = sc[base + 0], b0_ = bi[base + 0];
    const float s1_ = sc[base + 1], b1_ = bi[base + 1];
    const float s2_ = sc[base + 2], b2_ = bi[base + 2];
    const float s3_ = sc[base + 3], b3_ = bi[base + 3];
#pragma unroll
    for (int jj = 0; jj < 4; ++jj) {
      const int pos = p0 + wc * 64 + jj * 16 + nl;
      const float v0 = silu_f(s0_ * acc[i][jj][0] + b0_);
      const float v1 = silu_f(s1_ * acc[i][jj][1] + b1_);
      const float v2 = silu_f(s2_ * acc[i][jj][2] + b2_);
      const float v3 = silu_f(s3_ * acc[i][jj][3] + b3_);
      A01p[((size_t)b * 64 + (base >> 1)) * 4096 + pos]     = packbf(v0, v1);
      A01p[((size_t)b * 64 + (base >> 1) + 1) * 4096 + pos] = packbf(v2, v3);
    }
  }
}

// ---------------------------------------------------------------------------
// Depthwise dilated 3x3 + SiLU on packed a01; writes T img tiles directly.
__global__ __launch_bounds__(256)
void dwconv_pack_kernel(const unsigned* __restrict__ A01p, unsigned* __restrict__ Timg,
                        const float* __restrict__ w02, const float* __restrict__ s02, const float* __restrict__ b02,
                        const float* __restrict__ w12, const float* __restrict__ s12, const float* __restrict__ b12,
                        const float* __restrict__ w22, const float* __restrict__ s22, const float* __restrict__ b22)
{
  const int br = blockIdx.z;
  const int yb = blockIdx.y;
  const int b = yb >> 4, t16 = yb & 15, kstep = t16 >> 3, mm = t16 & 7;
  const int kq = (mm & 3) + ((mm >> 2) << 3);
  const int cbase = kstep * 64 + kq * 4;
  const int p = blockIdx.x * 256 + threadIdx.x;
  const int y = p >> 6, xx = p & 63;
  const int d = 3 + 2 * br;

  const float* wsel = br == 0 ? w02 : (br == 1 ? w12 : w22);
  const float* ssel = br == 0 ? s02 : (br == 1 ? s12 : s22);
  const float* bsel = br == 0 ? b02 : (br == 1 ? b12 : b22);

  float sum[8] = {};
  const unsigned* plane0 = A01p + ((size_t)b * 64 + (cbase >> 1)) * 4096;

#pragma unroll
  for (int u = -1; u <= 1; ++u) {
    const int yv = y + u * d;
    if ((unsigned)yv < 64u) {
#pragma unroll
      for (int v = -1; v <= 1; ++v) {
        const int xv = xx + v * d;
        if ((unsigned)xv < 64u) {
          const int idx = yv * 64 + xv;
          const int tap = (u + 1) * 3 + (v + 1);
#pragma unroll
          for (int q = 0; q < 4; ++q) {
            const int sub = q >> 1, jw = q & 1;
            const unsigned wv = plane0[(size_t)(sub * 8 + jw) * 4096 + idx];
            const int ch = cbase + sub * 16 + jw * 2;
            sum[q * 2 + 0] += wsel[(ch + 0) * 9 + tap] * bf_lo(wv);
            sum[q * 2 + 1] += wsel[(ch + 1) * 9 + tap] * bf_hi(wv);
          }
        }
      }
    }
  }

  unsigned wout[4];
#pragma unroll
  for (int h = 0; h < 4; ++h) {
    const int ch = cbase + (h >> 1) * 16 + (h & 1) * 2;
    const float va = silu_f(ssel[ch] * sum[h * 2] + bsel[ch]);
    const float vb = silu_f(ssel[ch + 1] * sum[h * 2 + 1] + bsel[ch + 1]);
    wout[h] = packbf(va, vb);
  }
  const int tile = ((br * 8 + b) * 2 + kstep) * 32 + (p >> 7);
  *(uint4*)(Timg + (size_t)tile * 4096 + (((mm << 7) + (p & 127)) << 2)) = *(uint4*)wout;
}

// ---------------------------------------------------------------------------
// B = sum_i silu(s_i*(W_i @ t_i)+b_i), 2-phase dbuf, XCD-swizzled 1D grid.
__global__ __launch_bounds__(512)
void gemm3branch_img_kernel(const unsigned* __restrict__ Timg, const unsigned* __restrict__ Wimg3,
                            const float* __restrict__ s0, const float* __restrict__ s1, const float* __restrict__ s2,
                            const float* __restrict__ b0, const float* __restrict__ b1, const float* __restrict__ b2,
                            unsigned* __restrict__ Bimg)
{
  XCD_DECODE_1024
  GEMM_IDS
  __shared__ unsigned Xp[2][4096], Wp[2][4096];

  float sum[2][4][4] = {};
  f32x4 acc[2][4];
#pragma unroll
  for (int i = 0; i < 2; ++i)
#pragma unroll
    for (int jj = 0; jj < 4; ++jj) acc[i][jj] = (f32x4){0.f, 0.f, 0.f, 0.f};

#define SRC_X3(st) (Timg + (((size_t)(((st) >> 1) * 8 + b) * 2 + ((st) & 1)) * 32 + pt) * 4096)
#define SRC_W3(st) (Wimg3 + (size_t)((st) >> 1) * 32768 + ((size_t)ocb_ * 2 + ((st) & 1)) * 4096)

  stage_tile_g(SRC_X3(0), Xp[0], tid);
  stage_tile_g(SRC_W3(0), Wp[0], tid);
  __syncthreads();

  for (int st = 0; st < 6; ++st) {
    const int cur = st & 1;
    if (st < 5) {
      stage_tile_g(SRC_X3(st + 1), Xp[cur ^ 1], tid);
      stage_tile_g(SRC_W3(st + 1), Wp[cur ^ 1], tid);
    }
    GEMM_KSTEP_B(acc, Xp[cur], Wp[cur])
    if (st & 1) {
      const int brn = st >> 1;
      const float* ss = brn == 0 ? s0 : (brn == 1 ? s1 : s2);
      const float* bs = brn == 0 ? b0 : (brn == 1 ? b1 : b2);
#pragma unroll
      for (int i = 0; i < 2; ++i) {
        const int base = oc0 + wr * 32 + i * 16 + 4 * g;
#pragma unroll
        for (int r = 0; r < 4; ++r) {
          const float s = ss[base + r], bb = bs[base + r];
#pragma unroll
          for (int jj = 0; jj < 4; ++jj) {
            sum[i][jj][r] += silu_f(s * acc[i][jj][r] + bb);
            acc[i][jj][r] = 0.f;
          }
        }
      }
    }
    __syncthreads();
  }
#undef SRC_X3
#undef SRC_W3

#pragma unroll
  for (int i = 0; i < 2; ++i) {
    const int ol = wr * 32 + i * 16 + 4 * g;
    const int kstep_g = (oc0 + ol) >> 6;
    const int kin = ol & 63;
    const int kq2 = kin >> 2;
    const int r4 = (kq2 & 3) + ((kq2 >> 3) << 2);
    const int sub = (kq2 >> 2) & 1;
#pragma unroll
    for (int jj = 0; jj < 4; ++jj) {
      const int pos = wc * 64 + jj * 16 + nl;
      uint2 wv;
      wv.x = packbf(sum[i][jj][0], sum[i][jj][1]);
      wv.y = packbf(sum[i][jj][2], sum[i][jj][3]);
      *(uint2*)(Bimg + ((size_t)(b * 8 + kstep_g) * 32 + pt) * 4096 + (((r4 << 7) + pos) << 2) + sub * 2) = wv;
    }
  }
}

// ---------------------------------------------------------------------------
// w3 GEMM (512->512) + fused silu*x + 4x4 pool + gap. r11 form (dbuf,
// counted vmcnt, setprio, bf16 x from Ximg2) + XCD-swizzled 1D grid.
__global__ __launch_bounds__(512)
void gemm_pool_img_kernel(const unsigned* __restrict__ Bimg, const unsigned* __restrict__ W3img,
                          const float* __restrict__ sc, const float* __restrict__ bi,
                          const unsigned* __restrict__ Ximg2, float* __restrict__ pooled2,
                          float* __restrict__ gapb)
{
  XCD_DECODE_1024
  const int p0 = pt * 128;
  const unsigned* Xb2 = Ximg2 + (size_t)b * 256 * 4096;
  GEMM_IDS
  __shared__ unsigned Xp[2][4096], Wp[2][4096];

  f32x4 acc[2][4];
#pragma unroll
  for (int i = 0; i < 2; ++i)
#pragma unroll
    for (int jj = 0; jj < 4; ++jj) acc[i][jj] = (f32x4){0.f, 0.f, 0.f, 0.f};

#define SRC_XP(st) (Bimg + ((size_t)(b * 8 + (st)) * 32 + pt) * 4096)
#define SRC_WP(st) (W3img + ((size_t)ocb_ * 8 + (st)) * 4096)

  stage_tile_g(SRC_XP(0), Xp[0], tid);
  stage_tile_g(SRC_WP(0), Wp[0], tid);
  stage_tile_g(SRC_XP(1), Xp[1], tid);
  stage_tile_g(SRC_WP(1), Wp[1], tid);

#pragma unroll
  for (int st = 0; st < 8; ++st) {
    const int cur = st & 1;
    if (st < 7) { VM_WAIT(4); } else { VM_WAIT(0); }
    SBAR();
    __builtin_amdgcn_s_setprio(1);
    GEMM_KSTEP_B(acc, Xp[cur], Wp[cur])
    __builtin_amdgcn_s_setprio(0);
    SBAR();
    if (st < 6) {
      stage_tile_g(SRC_XP(st + 2), Xp[cur], tid);
      stage_tile_g(SRC_WP(st + 2), Wp[cur], tid);
    }
  }
#undef SRC_XP
#undef SRC_WP

  // ---- LDS reductions: red[128 oc][16 pw] pool cells + gred[128] gap ----
  float* red  = (float*)Wp[0];           // 2048 floats
  float* gred = red + 2048;              // 128 floats
  for (int e = tid; e < 2176; e += 512) red[e] = 0.f;
  __syncthreads();

  float xsum[2][4] = {};
#pragma unroll
  for (int i = 0; i < 2; ++i) {
    const int olb = wr * 32 + i * 16 + 4 * g;          // oc quad base (mult 4)
    const int oc_ = oc0 + olb;
    const float4 s4 = *(const float4*)(sc + oc_);
    const float4 b4 = *(const float4*)(bi + oc_);
#pragma unroll
    for (int jj = 0; jj < 4; ++jj) {
      const int p = p0 + wc * 64 + jj * 16 + nl;
      const unsigned xw0 = Xb2[(size_t)(oc_ >> 1) * 4096 + p];
      const unsigned xw1 = Xb2[(size_t)((oc_ >> 1) + 1) * 4096 + p];
      const float xv[4] = {bf_lo(xw0), bf_hi(xw0), bf_lo(xw1), bf_hi(xw1)};
      const float sv[4] = {s4.x, s4.y, s4.z, s4.w};
      const float bv[4] = {b4.x, b4.y, b4.z, b4.w};
#pragma unroll
      for (int r = 0; r < 4; ++r) {
        xsum[i][r] += xv[r];
        float val = silu_f(sv[r] * acc[i][jj][r] + bv[r]) * xv[r];
        val += __shfl_xor(val, 1, 64);
        val += __shfl_xor(val, 2, 64);
        if ((nl & 3) == 0) {
          const int col = p & 63;
          atomicAdd(&red[(olb + r) * 16 + (col >> 2)], val);   // LDS atomic
        }
      }
    }
  }
  // gap partials: reduce xsum over the 16 nl lanes, add to gred[ol]
#pragma unroll
  for (int i = 0; i < 2; ++i)
#pragma unroll
    for (int r = 0; r < 4; ++r) {
      float v = xsum[i][r];
      v += __shfl_xor(v, 1, 64);
      v += __shfl_xor(v, 2, 64);
      v += __shfl_xor(v, 4, 64);
      v += __shfl_xor(v, 8, 64);
      if (nl == 0)
        atomicAdd(&gred[wr * 32 + i * 16 + 4 * g + r], v);     // LDS atomic
    }
  __syncthreads();

  {
    const int ph = pt >> 1;
    float* pdst = pooled2 + (size_t)(pt & 1) * (8ull * 512 * 256);
    for (int e = tid; e < 2048; e += 512) {
      const int ol = e >> 4, pw = e & 15;
      pdst[((size_t)b * 512 + oc0 + ol) * 256 + ph * 16 + pw] = red[e] * (1.f / 16.f);
    }
    if (tid < 128)
      atomicAdd(&gapb[b * 512 + oc0 + tid], gred[tid]);        // 128/block global
  }
}

// ---------------------------------------------------------------------------
// kv GEMM (pooledA+pooledB fp32 -> K img + V PV-layout tiles), 2-phase dbuf.
__global__ __launch_bounds__(512)
void gemm_kv_kernel(const float* __restrict__ pooled2, const unsigned* __restrict__ WKVimg,
                    const float* __restrict__ sc, const float* __restrict__ bi,
                    unsigned* __restrict__ Kimg, unsigned* __restrict__ Vimg)
{
  const int b = blockIdx.z, p0 = blockIdx.x * 128, oc0 = blockIdx.y * 128;
  const float* XbA = pooled2 + (size_t)b * 512 * 256 + p0;
  const float* XbB = XbA + 8ull * 512 * 256;
  GEMM_IDS
  __shared__ unsigned Xp[2][4096], Wp[2][4096];

  f32x4 acc[2][4];
#pragma unroll
  for (int i = 0; i < 2; ++i)
#pragma unroll
    for (int jj = 0; jj < 4; ++jj) acc[i][jj] = (f32x4){0.f, 0.f, 0.f, 0.f};

  {
    float vx[16];
    xload16_sum2(XbA, XbB, 256, tid, vx);
    stage_tile_g(WKVimg + (size_t)(oc0 >> 7) * 8 * 4096, Wp[0], tid);
    xwrite16(vx, Xp[0], tid);
  }
  __syncthreads();

  for (int st = 0; st < 8; ++st) {
    const int cur = st & 1;
    float vn[16];
    if (st < 7) {
      xload16_sum2(XbA + (size_t)((st + 1) * 64) * 256, XbB + (size_t)((st + 1) * 64) * 256,
                   256, tid, vn);
      stage_tile_g(WKVimg + ((size_t)(oc0 >> 7) * 8 + st + 1) * 4096, Wp[cur ^ 1], tid);
    }
    GEMM_KSTEP_B(acc, Xp[cur], Wp[cur])
    if (st < 7) xwrite16(vn, Xp[cur ^ 1], tid);
    __syncthreads();
  }

  const bool isK = (oc0 < 512);
#pragma unroll
  for (int i = 0; i < 2; ++i) {
    const int ocb = oc0 + wr * 32 + i * 16 + 4 * g;
#pragma unroll
    for (int jj = 0; jj < 4; ++jj) {
      const int pos = p0 + wc * 64 + jj * 16 + nl;
      float v[4];
#pragma unroll
      for (int r = 0; r < 4; ++r)
        v[r] = silu_f(sc[ocb + r] * acc[i][jj][r] + bi[ocb + r]);
      const int ch = pos >> 7, ml = pos & 127;
      if (isK) {
        const int h = ocb >> 6, d0 = ocb & 63;
        const int kq = d0 >> 2, sub = (kq >> 2) & 1;
        const int r4 = (kq & 3) + ((kq >> 3) << 2);
        unsigned* t = Kimg + ((size_t)(b * 8 + h) * 2 + ch) * 4096;
        uint2 wv;
        wv.x = packbf(v[0] * 0.125f, v[1] * 0.125f);
        wv.y = packbf(v[2] * 0.125f, v[3] * 0.125f);
        *(uint2*)(t + (((r4 << 7) + ml) << 2) + sub * 2) = wv;
      } else {
        const int h = (ocb - 512) >> 6, d0 = (ocb - 512) & 63;
        unsigned* t = Vimg + ((size_t)(b * 8 + h) * 2 + ch) * 4096;
        float ov[4];
#pragma unroll
        for (int r = 0; r < 4; ++r) ov[r] = __shfl_xor(v[r], 1, 64);
        if ((nl & 1) == 0) {
          const int s = (ml >> 1) & 1, m4 = ml >> 2;
#pragma unroll
          for (int r = 0; r < 4; ++r)
            t[((m4 * 64 + d0 + r) << 1) + s] = packbf(v[r], ov[r]);
        }
      }
    }
  }
}

// ---------------------------------------------------------------------------
// SE: gapb holds channel SUMS (fused in pool); scale by 1/4096 here.
__global__ __launch_bounds__(512)
void se_kernel(const float* __restrict__ gap,
               const float* __restrict__ wfc1, const float* __restrict__ bfc1,
               const float* __restrict__ wfc2, const float* __restrict__ bfc2,
               float* __restrict__ gate)
{
  const int b = blockIdx.x, tid = threadIdx.x;
  __shared__ float ylds[128];
  if (tid < 128) {
    float a = 0.f;
    for (int c = 0; c < 512; ++c) a += gap[b * 512 + c] * wfc1[tid * 512 + c];
    a = a * (1.f / 4096.f) + bfc1[tid];
    ylds[tid] = fminf(fmaxf(a, 0.f), 6.f);
  }
  __syncthreads();
  float g = 0.f;
  for (int j = 0; j < 128; ++j) g += ylds[j] * wfc2[tid * 128 + j];
  g += bfc2[tid];
  gate[b * 512 + tid] = 1.f / (1.f + __expf(-g));
}

// ---------------------------------------------------------------------------
// MFMA bf16 attention v3 (unchanged, verified).
__global__ __launch_bounds__(512)
void attn_mfma_kernel(const float* __restrict__ x, const unsigned* __restrict__ Kimg,
                      const unsigned* __restrict__ Vimg,
                      const float* __restrict__ gate, float* __restrict__ out)
{
  const int b = blockIdx.z, h = blockIdx.y;
  const int n0 = blockIdx.x * 128;
  const int tid = threadIdx.x;
  const int w = tid >> 6, lane = tid & 63;
  const int g = lane >> 4, nl = lane & 15;

  __shared__ unsigned lds[20480];          // Qp | K0 | K1 | V0 | V1 (80 KB)
  unsigned* Qp = lds;
  unsigned* Kb0 = lds + 4096;
  unsigned* Kb1 = lds + 8192;
  unsigned* Vb0 = lds + 12288;
  unsigned* Vb1 = lds + 16384;
  float* Osm = (float*)(lds + 4096);       // [64][132] overlay

  const size_t tbase = (size_t)(b * 8 + h) * 2 * 4096;

  stage_tile_g(Kimg + tbase, Kb0, tid);
  stage_tile_g(Vimg + tbase, Vb0, tid);
  stage_x_pack(x + ((size_t)b * 512 + h * 64) * 4096 + n0, 4096, Qp, tid);
  __syncthreads();
  stage_tile_g(Kimg + tbase + 4096, Kb1, tid);
  stage_tile_g(Vimg + tbase + 4096, Vb1, tid);

  float m_run = -1e30f, l_run = 0.f;
  f32x4 o[4];
#pragma unroll
  for (int i = 0; i < 4; ++i) o[i] = (f32x4){0.f, 0.f, 0.f, 0.f};

#pragma unroll
  for (int ch = 0; ch < 2; ++ch) {
    const unsigned* Kp = ch ? Kb1 : Kb0;
    const unsigned* Vp = ch ? Vb1 : Vb0;

    f32x4 s[8];
#pragma unroll
    for (int mb = 0; mb < 8; ++mb) s[mb] = (f32x4){0.f, 0.f, 0.f, 0.f};
#pragma unroll
    for (int ks = 0; ks < 2; ++ks) {
      const short8v qf = load_frag4(Qp, ks * 4 + g, w * 16 + nl);
#pragma unroll
      for (int mb = 0; mb < 8; ++mb) {
        const short8v kf = load_frag4(Kp, ks * 4 + g, mb * 16 + nl);
        s[mb] = __builtin_amdgcn_mfma_f32_16x16x32_bf16(kf, qf, s[mb], 0, 0, 0);
      }
    }

    float cm = -1e30f;
#pragma unroll
    for (int mb = 0; mb < 8; ++mb)
#pragma unroll
      for (int r = 0; r < 4; ++r) cm = fmaxf(cm, s[mb][r]);
    cm = fmaxf(cm, __shfl_xor(cm, 16, 64));
    cm = fmaxf(cm, __shfl_xor(cm, 32, 64));
    const float mnew = fmaxf(m_run, cm);
    const float corr = __expf(m_run - mnew);
    m_run = mnew;
    float cs = 0.f;
#pragma unroll
    for (int mb = 0; mb < 8; ++mb)
#pragma unroll
      for (int r = 0; r < 4; ++r) {
        const float p = __expf(s[mb][r] - mnew);
        s[mb][r] = p;
        cs += p;
      }
    cs += __shfl_xor(cs, 16, 64);
    cs += __shfl_xor(cs, 32, 64);
    l_run = l_run * corr + cs;
#pragma unroll
    for (int db = 0; db < 4; ++db)
#pragma unroll
      for (int r = 0; r < 4; ++r) o[db][r] *= corr;

#pragma unroll
    for (int ks = 0; ks < 4; ++ks) {
      FragU pf;
      pf.u[0] = packbf(s[2 * ks][0],     s[2 * ks][1]);
      pf.u[1] = packbf(s[2 * ks][2],     s[2 * ks][3]);
      pf.u[2] = packbf(s[2 * ks + 1][0], s[2 * ks + 1][1]);
      pf.u[3] = packbf(s[2 * ks + 1][2], s[2 * ks + 1][3]);
#pragma unroll
      for (int db = 0; db < 4; ++db) {
        FragU vf;
        const uint2 lo = *(const uint2*)(Vp + ((8 * ks + g) * 64 + db * 16 + nl) * 2);
        const uint2 hi = *(const uint2*)(Vp + ((8 * ks + 4 + g) * 64 + db * 16 + nl) * 2);
        vf.u[0] = lo.x; vf.u[1] = lo.y; vf.u[2] = hi.x; vf.u[3] = hi.y;
        o[db] = __builtin_amdgcn_mfma_f32_16x16x32_bf16(vf.v, pf.v, o[db], 0, 0, 0);
      }
    }
    __syncthreads();
  }

  const float inv = 1.f / l_run;
#pragma unroll
  for (int db = 0; db < 4; ++db)
#pragma unroll
    for (int r = 0; r < 4; ++r)
      Osm[(db * 16 + 4 * g + r) * 132 + w * 16 + nl] = o[db][r] * inv;
  __syncthreads();

  {
    const int n = tid & 127, t7 = tid >> 7;
    const int jw = t7 >> 1, half = t7 & 1;
#pragma unroll
    for (int i = 0; i < 16; ++i) {
      const int d = t7 + 4 * i;
      const int r4 = (i & 3) + ((i >> 3) << 2);
      const int sub = (i >> 2) & 1;
      const unsigned xw = Qp[(((r4 << 7) + n) << 2) + sub * 2 + jw];
      const float xv = half ? bf_hi(xw) : bf_lo(xw);
      const int c2 = h * 64 + d;
      const size_t off = ((size_t)b * 512 + c2) * 4096 + n0 + n;
      out[off] = Osm[d * 132 + n] + gate[b * 512 + c2] * xv;
    }
  }
}

// ---------------------------------------------------------------------------
extern "C" void kernel_launch(void* const* d_in, const int* in_sizes, int n_in,
                              void* d_out, int out_size, void* d_ws, size_t ws_size,
                              hipStream_t stream)
{
  const float* x    = (const float*)d_in[0];
  const float* w01  = (const float*)d_in[1];
  const float* s01  = (const float*)d_in[2];
  const float* b01  = (const float*)d_in[3];
  const float* w02  = (const float*)d_in[4];
  const float* s02  = (const float*)d_in[5];
  const float* b02  = (const float*)d_in[6];
  const float* w03  = (const float*)d_in[7];
  const float* s03  = (const float*)d_in[8];
  const float* b03  = (const float*)d_in[9];
  const float* w12  = (const float*)d_in[10];
  const float* s12  = (const float*)d_in[11];
  const float* b12  = (const float*)d_in[12];
  const float* w13  = (const float*)d_in[13];
  const float* s13  = (const float*)d_in[14];
  const float* b13  = (const float*)d_in[15];
  const float* w22  = (const float*)d_in[16];
  const float* s22  = (const float*)d_in[17];
  const float* b22  = (const float*)d_in[18];
  const float* w23  = (const float*)d_in[19];
  const float* s23  = (const float*)d_in[20];
  const float* b23  = (const float*)d_in[21];
  const float* w3   = (const float*)d_in[22];
  const float* s3   = (const float*)d_in[23];
  const float* b3   = (const float*)d_in[24];
  const float* wkv  = (const float*)d_in[25];
  const float* skv  = (const float*)d_in[26];
  const float* bkv  = (const float*)d_in[27];
  const float* wfc1 = (const float*)d_in[28];
  const float* bfc1 = (const float*)d_in[29];
  const float* wfc2 = (const float*)d_in[30];
  const float* bfc2 = (const float*)d_in[31];

  float* out = (float*)d_out;
  unsigned* wsu = (unsigned*)d_ws;

  // ws layout (u32 words):
  unsigned* Timg    = wsu;                        // 1536*4096 = 6,291,456
  float*    pooled2 = (float*)(wsu + 6291456);    // 2 x 1,048,576 = 2,097,152
  unsigned* Kimg    = wsu + 8388608;              //   524,288
  unsigned* Vimg    = wsu + 8912896;              //   524,288
  float*    gapb    = (float*)(wsu + 9437184);    //     4,096
  float*    gateb   = (float*)(wsu + 9441280);    //     4,096
  unsigned* Wimg    = wsu + 9445376;              //   524,288 (end 9,969,664 w = 38 MiB)

  // d_out aliasing (lifetimes disjoint):
  unsigned* A01p  = (unsigned*)d_out;             // [0, 2M w), dead after dwconv
  unsigned* Bimg  = (unsigned*)d_out;             // [0, 8M w), dead after pool
  unsigned* Ximg2 = (unsigned*)d_out + 8388608;   // [8M, 16.4M w), dead after pool

  prepack_w_kernel<<<128, 256, 0, stream>>>(w01, w03, w13, w23, w3, wkv, Wimg);
  gemm_a01_kernel<<<dim3(32, 1, 8), 512, 0, stream>>>(x, Wimg, s01, b01, A01p, Ximg2);
  dwconv_pack_kernel<<<dim3(16, 128, 3), 256, 0, stream>>>(A01p, Timg,
      w02, s02, b02, w12, s12, b12, w22, s22, b22);
  gemm3branch_img_kernel<<<1024, 512, 0, stream>>>(Timg, Wimg + 32768,
      s03, s13, s23, b03, b13, b23, Bimg);
  hipMemsetAsync(gapb, 0, 4096 * sizeof(float), stream);
  gemm_pool_img_kernel<<<1024, 512, 0, stream>>>(Bimg, Wimg + 131072,
      s3, b3, Ximg2, pooled2, gapb);
  gemm_kv_kernel<<<dim3(2, 8, 8), 512, 0, stream>>>(pooled2, Wimg + 262144, skv, bkv, Kimg, Vimg);
  se_kernel<<<8, 512, 0, stream>>>(gapb, wfc1, bfc1, wfc2, bfc2, gateb);
  attn_mfma_kernel<<<dim3(32, 8, 8), 512, 0, stream>>>(x, Kimg, Vimg, gateb, out);
}

// Round 15
// 232.935 us; speedup vs baseline: 1.0284x; 1.0081x over previous
//
#include <hip/hip_runtime.h>
#include <cstddef>

// ---------------------------------------------------------------------------
// _Mutilscal_MHSA — round 15: revert to the round-11 configuration (best
// measured, 233.2 us). The r13/14 XCD swizzle raised pool FETCH 37->83 MB
// (destroyed Bimg/Ximg2 dispatch-order locality) and is removed.
// Final structure:
//  - all pointwise GEMMs: bf16 MFMA, img-tile operands, global_load_lds
//  - pool: dbuf + counted vmcnt + setprio, bf16 x (Ximg2), LDS-reduced
//    atomic-free pooling, fused gap partials
//  - producer-packed K/V for attention; attn: swapped-QK^T MFMA flash with
//    fused SE-gate epilogue reading x from its Q LDS tile.
// ---------------------------------------------------------------------------

static __device__ __forceinline__ float silu_f(float v) {
  return v / (1.f + __expf(-v));
}

typedef __attribute__((ext_vector_type(8))) short short8v;   // bf16x8 frag
typedef __attribute__((ext_vector_type(4))) float f32x4;     // MFMA acc

union FragU { unsigned u[4]; short8v v; uint4 q; };

#define VM_WAIT(N) asm volatile("s_waitcnt vmcnt(" #N ")" ::: "memory")
#define SBAR()     asm volatile("s_barrier" ::: "memory")

static __device__ __forceinline__ unsigned short f2bf(float f) {
  unsigned u = __builtin_bit_cast(unsigned, f);
  u += 0x7fffu + ((u >> 16) & 1u);           // round-to-nearest-even
  return (unsigned short)(u >> 16);
}
static __device__ __forceinline__ unsigned packbf(float lo, float hi) {
  return (unsigned)f2bf(lo) | ((unsigned)f2bf(hi) << 16);
}
static __device__ __forceinline__ float bf_lo(unsigned w) {
  return __builtin_bit_cast(float, w << 16);
}
static __device__ __forceinline__ float bf_hi(unsigned w) {
  return __builtin_bit_cast(float, w & 0xffff0000u);
}

// async global->LDS, 16 B per lane (dest wave-linear: base + lane*16)
static __device__ __forceinline__ void gload16(const unsigned* gsrc, unsigned* ldst) {
  __builtin_amdgcn_global_load_lds(
      (const __attribute__((address_space(1))) unsigned*)gsrc,
      (__attribute__((address_space(3))) unsigned*)ldst, 16, 0, 0);
}

// stage one 4096-word img tile via global_load_lds (512 threads, 2x16B each)
static __device__ __forceinline__ void stage_tile_g(const unsigned* __restrict__ src,
                                                    unsigned* dst, int tid) {
  gload16(src + 4 * tid, dst + 4 * tid);
  gload16(src + 4 * (tid + 512), dst + 4 * (tid + 512));
}

// one fragment = one b128 read
static __device__ __forceinline__ short8v load_frag4(const unsigned* P, int ksg, int pos) {
  FragU f;
  f.q = *(const uint4*)(P + (((ksg << 7) + pos) << 2));
  return f.v;
}

// reg-staged fp32 operand: issue loads (early) ...
static __device__ __forceinline__ void xload16(const float* __restrict__ src, int ld,
                                               int tid, float v[16]) {
  const int pos = tid & 127, kg = tid >> 7;
  const float* p = src + pos + (size_t)(kg * 16) * ld;
#pragma unroll
  for (int i = 0; i < 16; ++i) v[i] = p[(size_t)i * ld];
}
// sum of two fp32 arrays (pooled partials)
static __device__ __forceinline__ void xload16_sum2(const float* __restrict__ a,
                                                    const float* __restrict__ b2, int ld,
                                                    int tid, float v[16]) {
  const int pos = tid & 127, kg = tid >> 7;
  const float* pA = a + pos + (size_t)(kg * 16) * ld;
  const float* pB = b2 + pos + (size_t)(kg * 16) * ld;
#pragma unroll
  for (int i = 0; i < 16; ++i) v[i] = pA[(size_t)i * ld] + pB[(size_t)i * ld];
}
// ... pack + LDS write (late)
static __device__ __forceinline__ void xwrite16(const float v[16], unsigned* Xp, int tid) {
  const int pos = tid & 127, kg = tid >> 7;
#pragma unroll
  for (int i2 = 0; i2 < 4; ++i2) {
    const int kq = kg * 4 + i2;
    const int r4 = (kq & 3) + ((kq >> 3) << 2);
    const int sub = (kq >> 2) & 1;
    uint2 wv;
    wv.x = packbf(v[i2 * 4 + 0], v[i2 * 4 + 1]);
    wv.y = packbf(v[i2 * 4 + 2], v[i2 * 4 + 3]);
    *(uint2*)(Xp + (((r4 << 7) + pos) << 2) + sub * 2) = wv;
  }
}
// packed-pair global store of a 64ch x 128pos x slice (coalesced per row)
static __device__ __forceinline__ void xstore_pairs(const float v[16],
                                                    unsigned* __restrict__ Xg_bst,
                                                    int p0, int tid) {
  const int pos = tid & 127, kg = tid >> 7;
#pragma unroll
  for (int m = 0; m < 8; ++m)
    Xg_bst[(size_t)(kg * 8 + m) * 4096 + p0 + pos] = packbf(v[2 * m], v[2 * m + 1]);
}

// legacy single-shot pack-stage (attn Q)
static __device__ __forceinline__ void stage_x_pack(const float* __restrict__ src, int ld,
                                                    unsigned* Xp, int tid) {
  float v[16];
  xload16(src, ld, tid, v);
  xwrite16(v, Xp, tid);
}

#define GEMM_IDS                                            \
  const int tid = threadIdx.x;                              \
  const int w = tid >> 6, lane = tid & 63;                  \
  const int g = lane >> 4, nl = lane & 15;                  \
  const int wr = w >> 1, wc = w & 1;

#define GEMM_KSTEP_B(ACC, XB, WB)                                                  \
  _Pragma("unroll")                                                                \
  for (int ks = 0; ks < 2; ++ks) {                                                 \
    const short8v a0 = load_frag4(WB, ks * 4 + g, wr * 32 + nl);                   \
    const short8v a1 = load_frag4(WB, ks * 4 + g, wr * 32 + 16 + nl);              \
    _Pragma("unroll")                                                              \
    for (int jj = 0; jj < 4; ++jj) {                                               \
      const short8v bfr = load_frag4(XB, ks * 4 + g, wc * 64 + jj * 16 + nl);      \
      ACC[0][jj] = __builtin_amdgcn_mfma_f32_16x16x32_bf16(a0, bfr, ACC[0][jj], 0, 0, 0); \
      ACC[1][jj] = __builtin_amdgcn_mfma_f32_16x16x32_bf16(a1, bfr, ACC[1][jj], 0, 0, 0); \
    }                                                                              \
  }

// ---------------------------------------------------------------------------
// Weight prepack: fp32 W[OC][K] -> img tiles (tile = to*(K/64)+tk).
__global__ __launch_bounds__(256)
void prepack_w_kernel(const float* __restrict__ w01, const float* __restrict__ w03,
                      const float* __restrict__ w13, const float* __restrict__ w23,
                      const float* __restrict__ w3, const float* __restrict__ wkv,
                      unsigned* __restrict__ img)
{
  const int t = blockIdx.x;
  const float* W; int K; int tile; unsigned* base;
  if (t < 8)       { W = w01; K = 512; tile = t;      base = img; }
  else if (t < 16) { W = w03; K = 128; tile = t - 8;  base = img + 32768; }
  else if (t < 24) { W = w13; K = 128; tile = t - 16; base = img + 65536; }
  else if (t < 32) { W = w23; K = 128; tile = t - 24; base = img + 98304; }
  else if (t < 64) { W = w3;  K = 512; tile = t - 32; base = img + 131072; }
  else             { W = wkv; K = 512; tile = t - 64; base = img + 262144; }
  const int nk = K >> 6;
  const int to = tile / nk, tk = tile - to * nk;
  unsigned* dst = base + (size_t)tile * 4096;
  for (int wi = threadIdx.x; wi < 4096; wi += 256) {
    const int r4 = wi >> 9, pos = (wi >> 2) & 127, sub = (wi >> 1) & 1, j = wi & 1;
    const int kq = (r4 & 3) + sub * 4 + ((r4 >> 2) << 3);
    const int k = tk * 64 + 4 * kq + 2 * j;
    const int oc = to * 128 + pos;
    dst[wi] = packbf(W[(size_t)oc * K + k], W[(size_t)oc * K + k + 1]);
  }
}

// ---------------------------------------------------------------------------
// a01 = silu(s01*(w01@x)+b01) as packed bf16 pairs A01p[b][c2][p].
// Also emits Ximg2[b][c2][p] = packed bf16 copy of x (byproduct).
__global__ __launch_bounds__(512)
void gemm_a01_kernel(const float* __restrict__ X, const unsigned* __restrict__ Wimg,
                     const float* __restrict__ sc, const float* __restrict__ bi,
                     unsigned* __restrict__ A01p, unsigned* __restrict__ Ximg2)
{
  const int b = blockIdx.z, p0 = blockIdx.x * 128;
  GEMM_IDS
  __shared__ unsigned Xp[2][4096], Wp[2][4096];
  const float* Xbase = X + (size_t)b * 512 * 4096 + p0;
  unsigned* Xg_b = Ximg2 + (size_t)b * 256 * 4096;

  f32x4 acc[2][4];
#pragma unroll
  for (int i = 0; i < 2; ++i)
#pragma unroll
    for (int jj = 0; jj < 4; ++jj) acc[i][jj] = (f32x4){0.f, 0.f, 0.f, 0.f};

  {
    float vx[16];
    xload16(Xbase, 4096, tid, vx);
    stage_tile_g(Wimg, Wp[0], tid);
    xwrite16(vx, Xp[0], tid);
    xstore_pairs(vx, Xg_b, p0, tid);                 // st=0 slice
  }
  __syncthreads();

  for (int st = 0; st < 8; ++st) {
    const int cur = st & 1;
    float vn[16];
    if (st < 7) {
      xload16(Xbase + (size_t)((st + 1) * 64) * 4096, 4096, tid, vn);
      stage_tile_g(Wimg + (size_t)(st + 1) * 4096, Wp[cur ^ 1], tid);
    }
    GEMM_KSTEP_B(acc, Xp[cur], Wp[cur])
    if (st < 7) {
      xwrite16(vn, Xp[cur ^ 1], tid);
      xstore_pairs(vn, Xg_b + (size_t)(32 * (st + 1)) * 4096, p0, tid);
    }
    __syncthreads();
  }

#pragma unroll
  for (int i = 0; i < 2; ++i) {
    const int base = wr * 32 + i * 16 + 4 * g;
    const float s0_ = sc[base + 0], b0_ = bi[base + 0];
    const float s1_ = sc[base + 1], b1_ = bi[base + 1];
    const float s2_ = sc[base + 2], b2_ = bi[base + 2];
    const float s3_ = sc[base + 3], b3_ = bi[base + 3];
#pragma unroll
    for (int jj = 0; jj < 4; ++jj) {
      const int pos = p0 + wc * 64 + jj * 16 + nl;
      const float v0 = silu_f(s0_ * acc[i][jj][0] + b0_);
      const float v1 = silu_f(s1_ * acc[i][jj][1] + b1_);
      const float v2 = silu_f(s2_ * acc[i][jj][2] + b2_);
      const float v3 = silu_f(s3_ * acc[i][jj][3] + b3_);
      A01p[((size_t)b * 64 + (base >> 1)) * 4096 + pos]     = packbf(v0, v1);
      A01p[((size_t)b * 64 + (base >> 1) + 1) * 4096 + pos] = packbf(v2, v3);
    }
  }
}

// ---------------------------------------------------------------------------
// Depthwise dilated 3x3 + SiLU on packed a01; writes T img tiles directly.
__global__ __launch_bounds__(256)
void dwconv_pack_kernel(const unsigned* __restrict__ A01p, unsigned* __restrict__ Timg,
                        const float* __restrict__ w02, const float* __restrict__ s02, const float* __restrict__ b02,
                        const float* __restrict__ w12, const float* __restrict__ s12, const float* __restrict__ b12,
                        const float* __restrict__ w22, const float* __restrict__ s22, const float* __restrict__ b22)
{
  const int br = blockIdx.z;
  const int yb = blockIdx.y;
  const int b = yb >> 4, t16 = yb & 15, kstep = t16 >> 3, mm = t16 & 7;
  const int kq = (mm & 3) + ((mm >> 2) << 3);
  const int cbase = kstep * 64 + kq * 4;
  const int p = blockIdx.x * 256 + threadIdx.x;
  const int y = p >> 6, xx = p & 63;
  const int d = 3 + 2 * br;

  const float* wsel = br == 0 ? w02 : (br == 1 ? w12 : w22);
  const float* ssel = br == 0 ? s02 : (br == 1 ? s12 : s22);
  const float* bsel = br == 0 ? b02 : (br == 1 ? b12 : b22);

  float sum[8] = {};
  const unsigned* plane0 = A01p + ((size_t)b * 64 + (cbase >> 1)) * 4096;

#pragma unroll
  for (int u = -1; u <= 1; ++u) {
    const int yv = y + u * d;
    if ((unsigned)yv < 64u) {
#pragma unroll
      for (int v = -1; v <= 1; ++v) {
        const int xv = xx + v * d;
        if ((unsigned)xv < 64u) {
          const int idx = yv * 64 + xv;
          const int tap = (u + 1) * 3 + (v + 1);
#pragma unroll
          for (int q = 0; q < 4; ++q) {
            const int sub = q >> 1, jw = q & 1;
            const unsigned wv = plane0[(size_t)(sub * 8 + jw) * 4096 + idx];
            const int ch = cbase + sub * 16 + jw * 2;
            sum[q * 2 + 0] += wsel[(ch + 0) * 9 + tap] * bf_lo(wv);
            sum[q * 2 + 1] += wsel[(ch + 1) * 9 + tap] * bf_hi(wv);
          }
        }
      }
    }
  }

  unsigned wout[4];
#pragma unroll
  for (int h = 0; h < 4; ++h) {
    const int ch = cbase + (h >> 1) * 16 + (h & 1) * 2;
    const float va = silu_f(ssel[ch] * sum[h * 2] + bsel[ch]);
    const float vb = silu_f(ssel[ch + 1] * sum[h * 2 + 1] + bsel[ch + 1]);
    wout[h] = packbf(va, vb);
  }
  const int tile = ((br * 8 + b) * 2 + kstep) * 32 + (p >> 7);
  *(uint4*)(Timg + (size_t)tile * 4096 + (((mm << 7) + (p & 127)) << 2)) = *(uint4*)wout;
}

// ---------------------------------------------------------------------------
// B = sum_i silu(s_i*(W_i @ t_i)+b_i), 2-phase dbuf (round-7 form).
__global__ __launch_bounds__(512)
void gemm3branch_img_kernel(const unsigned* __restrict__ Timg, const unsigned* __restrict__ Wimg3,
                            const float* __restrict__ s0, const float* __restrict__ s1, const float* __restrict__ s2,
                            const float* __restrict__ b0, const float* __restrict__ b1, const float* __restrict__ b2,
                            unsigned* __restrict__ Bimg)
{
  const int b = blockIdx.z, pt = blockIdx.x, oc0 = blockIdx.y * 128;
  GEMM_IDS
  __shared__ unsigned Xp[2][4096], Wp[2][4096];

  float sum[2][4][4] = {};
  f32x4 acc[2][4];
#pragma unroll
  for (int i = 0; i < 2; ++i)
#pragma unroll
    for (int jj = 0; jj < 4; ++jj) acc[i][jj] = (f32x4){0.f, 0.f, 0.f, 0.f};

#define SRC_X3(st) (Timg + (((size_t)(((st) >> 1) * 8 + b) * 2 + ((st) & 1)) * 32 + pt) * 4096)
#define SRC_W3(st) (Wimg3 + (size_t)((st) >> 1) * 32768 + ((size_t)(oc0 >> 7) * 2 + ((st) & 1)) * 4096)

  stage_tile_g(SRC_X3(0), Xp[0], tid);
  stage_tile_g(SRC_W3(0), Wp[0], tid);
  __syncthreads();

  for (int st = 0; st < 6; ++st) {
    const int cur = st & 1;
    if (st < 5) {
      stage_tile_g(SRC_X3(st + 1), Xp[cur ^ 1], tid);
      stage_tile_g(SRC_W3(st + 1), Wp[cur ^ 1], tid);
    }
    GEMM_KSTEP_B(acc, Xp[cur], Wp[cur])
    if (st & 1) {
      const int brn = st >> 1;
      const float* ss = brn == 0 ? s0 : (brn == 1 ? s1 : s2);
      const float* bs = brn == 0 ? b0 : (brn == 1 ? b1 : b2);
#pragma unroll
      for (int i = 0; i < 2; ++i) {
        const int base = oc0 + wr * 32 + i * 16 + 4 * g;
#pragma unroll
        for (int r = 0; r < 4; ++r) {
          const float s = ss[base + r], bb = bs[base + r];
#pragma unroll
          for (int jj = 0; jj < 4; ++jj) {
            sum[i][jj][r] += silu_f(s * acc[i][jj][r] + bb);
            acc[i][jj][r] = 0.f;
          }
        }
      }
    }
    __syncthreads();
  }
#undef SRC_X3
#undef SRC_W3

#pragma unroll
  for (int i = 0; i < 2; ++i) {
    const int ol = wr * 32 + i * 16 + 4 * g;
    const int kstep_g = (oc0 + ol) >> 6;
    const int kin = ol & 63;
    const int kq2 = kin >> 2;
    const int r4 = (kq2 & 3) + ((kq2 >> 3) << 2);
    const int sub = (kq2 >> 2) & 1;
#pragma unroll
    for (int jj = 0; jj < 4; ++jj) {
      const int pos = wc * 64 + jj * 16 + nl;
      uint2 wv;
      wv.x = packbf(sum[i][jj][0], sum[i][jj][1]);
      wv.y = packbf(sum[i][jj][2], sum[i][jj][3]);
      *(uint2*)(Bimg + ((size_t)(b * 8 + kstep_g) * 32 + pt) * 4096 + (((r4 << 7) + pos) << 2) + sub * 2) = wv;
    }
  }
}

// ---------------------------------------------------------------------------
// w3 GEMM (512->512) from B img + fused silu*x + 4x4 pool (atomic-free,
// LDS-reduced) + fused gap partials. x from Ximg2 (bf16). Counted-vmcnt
// pipeline + setprio around MFMA cluster. (r11 form, best measured.)
__global__ __launch_bounds__(512)
void gemm_pool_img_kernel(const unsigned* __restrict__ Bimg, const unsigned* __restrict__ W3img,
                          const float* __restrict__ sc, const float* __restrict__ bi,
                          const unsigned* __restrict__ Ximg2, float* __restrict__ pooled2,
                          float* __restrict__ gapb)
{
  const int b = blockIdx.z, pt = blockIdx.x, oc0 = blockIdx.y * 128;
  const int p0 = pt * 128;
  const unsigned* Xb2 = Ximg2 + (size_t)b * 256 * 4096;
  GEMM_IDS
  __shared__ unsigned Xp[2][4096], Wp[2][4096];

  f32x4 acc[2][4];
#pragma unroll
  for (int i = 0; i < 2; ++i)
#pragma unroll
    for (int jj = 0; jj < 4; ++jj) acc[i][jj] = (f32x4){0.f, 0.f, 0.f, 0.f};

#define SRC_XP(st) (Bimg + ((size_t)(b * 8 + (st)) * 32 + pt) * 4096)
#define SRC_WP(st) (W3img + ((size_t)(oc0 >> 7) * 8 + (st)) * 4096)

  stage_tile_g(SRC_XP(0), Xp[0], tid);
  stage_tile_g(SRC_WP(0), Wp[0], tid);
  stage_tile_g(SRC_XP(1), Xp[1], tid);
  stage_tile_g(SRC_WP(1), Wp[1], tid);

#pragma unroll
  for (int st = 0; st < 8; ++st) {
    const int cur = st & 1;
    if (st < 7) { VM_WAIT(4); } else { VM_WAIT(0); }
    SBAR();
    __builtin_amdgcn_s_setprio(1);
    GEMM_KSTEP_B(acc, Xp[cur], Wp[cur])
    __builtin_amdgcn_s_setprio(0);
    SBAR();
    if (st < 6) {
      stage_tile_g(SRC_XP(st + 2), Xp[cur], tid);
      stage_tile_g(SRC_WP(st + 2), Wp[cur], tid);
    }
  }
#undef SRC_XP
#undef SRC_WP

  // ---- LDS reductions: red[128 oc][16 pw] pool cells + gred[128] gap ----
  float* red  = (float*)Wp[0];           // 2048 floats
  float* gred = red + 2048;              // 128 floats
  for (int e = tid; e < 2176; e += 512) red[e] = 0.f;
  __syncthreads();

  float xsum[2][4] = {};
#pragma unroll
  for (int i = 0; i < 2; ++i) {
    const int olb = wr * 32 + i * 16 + 4 * g;          // oc quad base (mult 4)
    const int oc_ = oc0 + olb;
    const float4 s4 = *(const float4*)(sc + oc_);
    const float4 b4 = *(const float4*)(bi + oc_);
#pragma unroll
    for (int jj = 0; jj < 4; ++jj) {
      const int p = p0 + wc * 64 + jj * 16 + nl;
      const unsigned xw0 = Xb2[(size_t)(oc_ >> 1) * 4096 + p];
      const unsigned xw1 = Xb2[(size_t)((oc_ >> 1) + 1) * 4096 + p];
      const float xv[4] = {bf_lo(xw0), bf_hi(xw0), bf_lo(xw1), bf_hi(xw1)};
      const float sv[4] = {s4.x, s4.y, s4.z, s4.w};
      const float bv[4] = {b4.x, b4.y, b4.z, b4.w};
#pragma unroll
      for (int r = 0; r < 4; ++r) {
        xsum[i][r] += xv[r];
        float val = silu_f(sv[r] * acc[i][jj][r] + bv[r]) * xv[r];
        val += __shfl_xor(val, 1, 64);
        val += __shfl_xor(val, 2, 64);
        if ((nl & 3) == 0) {
          const int col = p & 63;
          atomicAdd(&red[(olb + r) * 16 + (col >> 2)], val);   // LDS atomic
        }
      }
    }
  }
  // gap partials: reduce xsum over the 16 nl lanes, add to gred[ol]
#pragma unroll
  for (int i = 0; i < 2; ++i)
#pragma unroll
    for (int r = 0; r < 4; ++r) {
      float v = xsum[i][r];
      v += __shfl_xor(v, 1, 64);
      v += __shfl_xor(v, 2, 64);
      v += __shfl_xor(v, 4, 64);
      v += __shfl_xor(v, 8, 64);
      if (nl == 0)
        atomicAdd(&gred[wr * 32 + i * 16 + 4 * g + r], v);     // LDS atomic
    }
  __syncthreads();

  {
    const int ph = pt >> 1;
    float* pdst = pooled2 + (size_t)(pt & 1) * (8ull * 512 * 256);
    for (int e = tid; e < 2048; e += 512) {
      const int ol = e >> 4, pw = e & 15;
      pdst[((size_t)b * 512 + oc0 + ol) * 256 + ph * 16 + pw] = red[e] * (1.f / 16.f);
    }
    if (tid < 128)
      atomicAdd(&gapb[b * 512 + oc0 + tid], gred[tid]);        // 128/block global
  }
}

// ---------------------------------------------------------------------------
// kv GEMM (pooledA+pooledB fp32 -> K img + V PV-layout tiles), 2-phase dbuf.
__global__ __launch_bounds__(512)
void gemm_kv_kernel(const float* __restrict__ pooled2, const unsigned* __restrict__ WKVimg,
                    const float* __restrict__ sc, const float* __restrict__ bi,
                    unsigned* __restrict__ Kimg, unsigned* __restrict__ Vimg)
{
  const int b = blockIdx.z, p0 = blockIdx.x * 128, oc0 = blockIdx.y * 128;
  const float* XbA = pooled2 + (size_t)b * 512 * 256 + p0;
  const float* XbB = XbA + 8ull * 512 * 256;
  GEMM_IDS
  __shared__ unsigned Xp[2][4096], Wp[2][4096];

  f32x4 acc[2][4];
#pragma unroll
  for (int i = 0; i < 2; ++i)
#pragma unroll
    for (int jj = 0; jj < 4; ++jj) acc[i][jj] = (f32x4){0.f, 0.f, 0.f, 0.f};

  {
    float vx[16];
    xload16_sum2(XbA, XbB, 256, tid, vx);
    stage_tile_g(WKVimg + (size_t)(oc0 >> 7) * 8 * 4096, Wp[0], tid);
    xwrite16(vx, Xp[0], tid);
  }
  __syncthreads();

  for (int st = 0; st < 8; ++st) {
    const int cur = st & 1;
    float vn[16];
    if (st < 7) {
      xload16_sum2(XbA + (size_t)((st + 1) * 64) * 256, XbB + (size_t)((st + 1) * 64) * 256,
                   256, tid, vn);
      stage_tile_g(WKVimg + ((size_t)(oc0 >> 7) * 8 + st + 1) * 4096, Wp[cur ^ 1], tid);
    }
    GEMM_KSTEP_B(acc, Xp[cur], Wp[cur])
    if (st < 7) xwrite16(vn, Xp[cur ^ 1], tid);
    __syncthreads();
  }

  const bool isK = (oc0 < 512);
#pragma unroll
  for (int i = 0; i < 2; ++i) {
    const int ocb = oc0 + wr * 32 + i * 16 + 4 * g;
#pragma unroll
    for (int jj = 0; jj < 4; ++jj) {
      const int pos = p0 + wc * 64 + jj * 16 + nl;
      float v[4];
#pragma unroll
      for (int r = 0; r < 4; ++r)
        v[r] = silu_f(sc[ocb + r] * acc[i][jj][r] + bi[ocb + r]);
      const int ch = pos >> 7, ml = pos & 127;
      if (isK) {
        const int h = ocb >> 6, d0 = ocb & 63;
        const int kq = d0 >> 2, sub = (kq >> 2) & 1;
        const int r4 = (kq & 3) + ((kq >> 3) << 2);
        unsigned* t = Kimg + ((size_t)(b * 8 + h) * 2 + ch) * 4096;
        uint2 wv;
        wv.x = packbf(v[0] * 0.125f, v[1] * 0.125f);
        wv.y = packbf(v[2] * 0.125f, v[3] * 0.125f);
        *(uint2*)(t + (((r4 << 7) + ml) << 2) + sub * 2) = wv;
      } else {
        const int h = (ocb - 512) >> 6, d0 = (ocb - 512) & 63;
        unsigned* t = Vimg + ((size_t)(b * 8 + h) * 2 + ch) * 4096;
        float ov[4];
#pragma unroll
        for (int r = 0; r < 4; ++r) ov[r] = __shfl_xor(v[r], 1, 64);
        if ((nl & 1) == 0) {
          const int s = (ml >> 1) & 1, m4 = ml >> 2;
#pragma unroll
          for (int r = 0; r < 4; ++r)
            t[((m4 * 64 + d0 + r) << 1) + s] = packbf(v[r], ov[r]);
        }
      }
    }
  }
}

// ---------------------------------------------------------------------------
// SE: gapb holds channel SUMS (fused in pool); scale by 1/4096 here.
__global__ __launch_bounds__(512)
void se_kernel(const float* __restrict__ gap,
               const float* __restrict__ wfc1, const float* __restrict__ bfc1,
               const float* __restrict__ wfc2, const float* __restrict__ bfc2,
               float* __restrict__ gate)
{
  const int b = blockIdx.x, tid = threadIdx.x;
  __shared__ float ylds[128];
  if (tid < 128) {
    float a = 0.f;
    for (int c = 0; c < 512; ++c) a += gap[b * 512 + c] * wfc1[tid * 512 + c];
    a = a * (1.f / 4096.f) + bfc1[tid];
    ylds[tid] = fminf(fmaxf(a, 0.f), 6.f);
  }
  __syncthreads();
  float g = 0.f;
  for (int j = 0; j < 128; ++j) g += ylds[j] * wfc2[tid * 128 + j];
  g += bfc2[tid];
  gate[b * 512 + tid] = 1.f / (1.f + __expf(-g));
}

// ---------------------------------------------------------------------------
// MFMA bf16 attention v3 (unchanged, verified).
__global__ __launch_bounds__(512)
void attn_mfma_kernel(const float* __restrict__ x, const unsigned* __restrict__ Kimg,
                      const unsigned* __restrict__ Vimg,
                      const float* __restrict__ gate, float* __restrict__ out)
{
  const int b = blockIdx.z, h = blockIdx.y;
  const int n0 = blockIdx.x * 128;
  const int tid = threadIdx.x;
  const int w = tid >> 6, lane = tid & 63;
  const int g = lane >> 4, nl = lane & 15;

  __shared__ unsigned lds[20480];          // Qp | K0 | K1 | V0 | V1 (80 KB)
  unsigned* Qp = lds;
  unsigned* Kb0 = lds + 4096;
  unsigned* Kb1 = lds + 8192;
  unsigned* Vb0 = lds + 12288;
  unsigned* Vb1 = lds + 16384;
  float* Osm = (float*)(lds + 4096);       // [64][132] overlay

  const size_t tbase = (size_t)(b * 8 + h) * 2 * 4096;

  stage_tile_g(Kimg + tbase, Kb0, tid);
  stage_tile_g(Vimg + tbase, Vb0, tid);
  stage_x_pack(x + ((size_t)b * 512 + h * 64) * 4096 + n0, 4096, Qp, tid);
  __syncthreads();
  stage_tile_g(Kimg + tbase + 4096, Kb1, tid);
  stage_tile_g(Vimg + tbase + 4096, Vb1, tid);

  float m_run = -1e30f, l_run = 0.f;
  f32x4 o[4];
#pragma unroll
  for (int i = 0; i < 4; ++i) o[i] = (f32x4){0.f, 0.f, 0.f, 0.f};

#pragma unroll
  for (int ch = 0; ch < 2; ++ch) {
    const unsigned* Kp = ch ? Kb1 : Kb0;
    const unsigned* Vp = ch ? Vb1 : Vb0;

    f32x4 s[8];
#pragma unroll
    for (int mb = 0; mb < 8; ++mb) s[mb] = (f32x4){0.f, 0.f, 0.f, 0.f};
#pragma unroll
    for (int ks = 0; ks < 2; ++ks) {
      const short8v qf = load_frag4(Qp, ks * 4 + g, w * 16 + nl);
#pragma unroll
      for (int mb = 0; mb < 8; ++mb) {
        const short8v kf = load_frag4(Kp, ks * 4 + g, mb * 16 + nl);
        s[mb] = __builtin_amdgcn_mfma_f32_16x16x32_bf16(kf, qf, s[mb], 0, 0, 0);
      }
    }

    float cm = -1e30f;
#pragma unroll
    for (int mb = 0; mb < 8; ++mb)
#pragma unroll
      for (int r = 0; r < 4; ++r) cm = fmaxf(cm, s[mb][r]);
    cm = fmaxf(cm, __shfl_xor(cm, 16, 64));
    cm = fmaxf(cm, __shfl_xor(cm, 32, 64));
    const float mnew = fmaxf(m_run, cm);
    const float corr = __expf(m_run - mnew);
    m_run = mnew;
    float cs = 0.f;
#pragma unroll
    for (int mb = 0; mb < 8; ++mb)
#pragma unroll
      for (int r = 0; r < 4; ++r) {
        const float p = __expf(s[mb][r] - mnew);
        s[mb][r] = p;
        cs += p;
      }
    cs += __shfl_xor(cs, 16, 64);
    cs += __shfl_xor(cs, 32, 64);
    l_run = l_run * corr + cs;
#pragma unroll
    for (int db = 0; db < 4; ++db)
#pragma unroll
      for (int r = 0; r < 4; ++r) o[db][r] *= corr;

#pragma unroll
    for (int ks = 0; ks < 4; ++ks) {
      FragU pf;
      pf.u[0] = packbf(s[2 * ks][0],     s[2 * ks][1]);
      pf.u[1] = packbf(s[2 * ks][2],     s[2 * ks][3]);
      pf.u[2] = packbf(s[2 * ks + 1][0], s[2 * ks + 1][1]);
      pf.u[3] = packbf(s[2 * ks + 1][2], s[2 * ks + 1][3]);
#pragma unroll
      for (int db = 0; db < 4; ++db) {
        FragU vf;
        const uint2 lo = *(const uint2*)(Vp + ((8 * ks + g) * 64 + db * 16 + nl) * 2);
        const uint2 hi = *(const uint2*)(Vp + ((8 * ks + 4 + g) * 64 + db * 16 + nl) * 2);
        vf.u[0] = lo.x; vf.u[1] = lo.y; vf.u[2] = hi.x; vf.u[3] = hi.y;
        o[db] = __builtin_amdgcn_mfma_f32_16x16x32_bf16(vf.v, pf.v, o[db], 0, 0, 0);
      }
    }
    __syncthreads();
  }

  const float inv = 1.f / l_run;
#pragma unroll
  for (int db = 0; db < 4; ++db)
#pragma unroll
    for (int r = 0; r < 4; ++r)
      Osm[(db * 16 + 4 * g + r) * 132 + w * 16 + nl] = o[db][r] * inv;
  __syncthreads();

  {
    const int n = tid & 127, t7 = tid >> 7;
    const int jw = t7 >> 1, half = t7 & 1;
#pragma unroll
    for (int i = 0; i < 16; ++i) {
      const int d = t7 + 4 * i;
      const int r4 = (i & 3) + ((i >> 3) << 2);
      const int sub = (i >> 2) & 1;
      const unsigned xw = Qp[(((r4 << 7) + n) << 2) + sub * 2 + jw];
      const float xv = half ? bf_hi(xw) : bf_lo(xw);
      const int c2 = h * 64 + d;
      const size_t off = ((size_t)b * 512 + c2) * 4096 + n0 + n;
      out[off] = Osm[d * 132 + n] + gate[b * 512 + c2] * xv;
    }
  }
}

// ---------------------------------------------------------------------------
extern "C" void kernel_launch(void* const* d_in, const int* in_sizes, int n_in,
                              void* d_out, int out_size, void* d_ws, size_t ws_size,
                              hipStream_t stream)
{
  const float* x    = (const float*)d_in[0];
  const float* w01  = (const float*)d_in[1];
  const float* s01  = (const float*)d_in[2];
  const float* b01  = (const float*)d_in[3];
  const float* w02  = (const float*)d_in[4];
  const float* s02  = (const float*)d_in[5];
  const float* b02  = (const float*)d_in[6];
  const float* w03  = (const float*)d_in[7];
  const float* s03  = (const float*)d_in[8];
  const float* b03  = (const float*)d_in[9];
  const float* w12  = (const float*)d_in[10];
  const float* s12  = (const float*)d_in[11];
  const float* b12  = (const float*)d_in[12];
  const float* w13  = (const float*)d_in[13];
  const float* s13  = (const float*)d_in[14];
  const float* b13  = (const float*)d_in[15];
  const float* w22  = (const float*)d_in[16];
  const float* s22  = (const float*)d_in[17];
  const float* b22  = (const float*)d_in[18];
  const float* w23  = (const float*)d_in[19];
  const float* s23  = (const float*)d_in[20];
  const float* b23  = (const float*)d_in[21];
  const float* w3   = (const float*)d_in[22];
  const float* s3   = (const float*)d_in[23];
  const float* b3   = (const float*)d_in[24];
  const float* wkv  = (const float*)d_in[25];
  const float* skv  = (const float*)d_in[26];
  const float* bkv  = (const float*)d_in[27];
  const float* wfc1 = (const float*)d_in[28];
  const float* bfc1 = (const float*)d_in[29];
  const float* wfc2 = (const float*)d_in[30];
  const float* bfc2 = (const float*)d_in[31];

  float* out = (float*)d_out;
  unsigned* wsu = (unsigned*)d_ws;

  // ws layout (u32 words):
  unsigned* Timg    = wsu;                        // 1536*4096 = 6,291,456
  float*    pooled2 = (float*)(wsu + 6291456);    // 2 x 1,048,576 = 2,097,152
  unsigned* Kimg    = wsu + 8388608;              //   524,288
  unsigned* Vimg    = wsu + 8912896;              //   524,288
  float*    gapb    = (float*)(wsu + 9437184);    //     4,096
  float*    gateb   = (float*)(wsu + 9441280);    //     4,096
  unsigned* Wimg    = wsu + 9445376;              //   524,288 (end 9,969,664 w = 38 MiB)

  // d_out aliasing (lifetimes disjoint):
  unsigned* A01p  = (unsigned*)d_out;             // [0, 2M w), dead after dwconv
  unsigned* Bimg  = (unsigned*)d_out;             // [0, 8M w), dead after pool
  unsigned* Ximg2 = (unsigned*)d_out + 8388608;   // [8M, 16.4M w), dead after pool

  prepack_w_kernel<<<128, 256, 0, stream>>>(w01, w03, w13, w23, w3, wkv, Wimg);
  gemm_a01_kernel<<<dim3(32, 1, 8), 512, 0, stream>>>(x, Wimg, s01, b01, A01p, Ximg2);
  dwconv_pack_kernel<<<dim3(16, 128, 3), 256, 0, stream>>>(A01p, Timg,
      w02, s02, b02, w12, s12, b12, w22, s22, b22);
  gemm3branch_img_kernel<<<dim3(32, 4, 8), 512, 0, stream>>>(Timg, Wimg + 32768,
      s03, s13, s23, b03, b13, b23, Bimg);
  hipMemsetAsync(gapb, 0, 4096 * sizeof(float), stream);
  gemm_pool_img_kernel<<<dim3(32, 4, 8), 512, 0, stream>>>(Bimg, Wimg + 131072,
      s3, b3, Ximg2, pooled2, gapb);
  gemm_kv_kernel<<<dim3(2, 8, 8), 512, 0, stream>>>(pooled2, Wimg + 262144, skv, bkv, Kimg, Vimg);
  se_kernel<<<8, 512, 0, stream>>>(gapb, wfc1, bfc1, wfc2, bfc2, gateb);
  attn_mfma_kernel<<<dim3(32, 8, 8), 512, 0, stream>>>(x, Kimg, Vimg, gateb, out);
}